// Round 1
// baseline (1052.960 us; speedup 1.0000x reference)
//
#include <hip/hip_runtime.h>

#define B_  2
#define L_  2048
#define D_  1024
#define DI_ 2048
#define NS  16
#define RR  64
#define MM  (B_*L_)      // 4096 rows
#define NC  32           // scan chunks
#define CL  (L_/NC)      // 64 steps per chunk

// ---------------------------------------------------------------------------
// C[M,N] = A[M,K] @ W[N,K]^T + bias[N]   (fp32, BM=BN=64, BK=16, 4x4/thread)
// ---------------------------------------------------------------------------
__global__ __launch_bounds__(256)
void gemm64(const float* __restrict__ A, const float* __restrict__ W,
            const float* __restrict__ bias, float* __restrict__ C,
            int M, int N, int K)
{
    __shared__ float As[16][68];   // stride 68: aligned float4 reads, spread banks
    __shared__ float Ws[16][68];
    const int t  = threadIdx.x;
    const int bm = blockIdx.y * 64, bn = blockIdx.x * 64;
    const int tx = t & 15, ty = t >> 4;
    const int lr = t >> 2;            // staging row 0..63
    const int lk = (t & 3) << 2;      // staging k 0,4,8,12

    float acc[4][4] = {};
    for (int k0 = 0; k0 < K; k0 += 16) {
        float4 av = *(const float4*)(A + (size_t)(bm + lr) * K + k0 + lk);
        float4 wv = *(const float4*)(W + (size_t)(bn + lr) * K + k0 + lk);
        As[lk+0][lr] = av.x; As[lk+1][lr] = av.y; As[lk+2][lr] = av.z; As[lk+3][lr] = av.w;
        Ws[lk+0][lr] = wv.x; Ws[lk+1][lr] = wv.y; Ws[lk+2][lr] = wv.z; Ws[lk+3][lr] = wv.w;
        __syncthreads();
        #pragma unroll
        for (int kk = 0; kk < 16; ++kk) {
            float4 a4 = *(const float4*)&As[kk][ty << 2];
            float4 b4 = *(const float4*)&Ws[kk][tx << 2];
            float a[4] = {a4.x, a4.y, a4.z, a4.w};
            float b[4] = {b4.x, b4.y, b4.z, b4.w};
            #pragma unroll
            for (int i = 0; i < 4; ++i)
                #pragma unroll
                for (int j = 0; j < 4; ++j)
                    acc[i][j] = fmaf(a[i], b[j], acc[i][j]);
        }
        __syncthreads();
    }
    const int row = bm + (ty << 2), col = bn + (tx << 2);
    float4 bv = *(const float4*)(bias + col);
    #pragma unroll
    for (int i = 0; i < 4; ++i) {
        float4 o;
        o.x = acc[i][0] + bv.x; o.y = acc[i][1] + bv.y;
        o.z = acc[i][2] + bv.z; o.w = acc[i][3] + bv.w;
        *(float4*)(C + (size_t)(row + i) * N + col) = o;
    }
}

// ---------------------------------------------------------------------------
// u = silu(depthwise_conv3(h) + conv_b)   (cross-correlation, zero pad 1)
// ---------------------------------------------------------------------------
__global__ __launch_bounds__(256)
void conv_silu(const float* __restrict__ h, const float* __restrict__ cw,
               const float* __restrict__ cb, float* __restrict__ u)
{
    size_t idx = (size_t)blockIdx.x * 256 + threadIdx.x;   // B*L*DI
    int    di  = idx & (DI_ - 1);
    size_t bl  = idx >> 11;            // /DI_
    int    l   = (int)(bl & (L_ - 1));
    float s = cb[di] + h[idx] * cw[di * 3 + 1];
    if (l > 0)      s += h[idx - DI_] * cw[di * 3 + 0];
    if (l < L_ - 1) s += h[idx + DI_] * cw[di * 3 + 2];
    u[idx] = s / (1.f + __expf(-s));   // silu
}

// ---------------------------------------------------------------------------
// xdbl[M,80] = u[M,DI] @ xw[80,DI]^T + xb
// ---------------------------------------------------------------------------
__global__ __launch_bounds__(256)
void xproj(const float* __restrict__ u, const float* __restrict__ xw,
           const float* __restrict__ xb, float* __restrict__ xdbl)
{
    __shared__ float ut[32][33];
    __shared__ float wt[80][33];
    const int t    = threadIdx.x;
    const int row0 = blockIdx.x * 32;
    const int r    = t & 31;
    const int j0   = (t >> 5) * 10;
    float acc[10] = {};
    for (int k0 = 0; k0 < DI_; k0 += 32) {
        {   // stage u tile 32x32
            int sr = t >> 3, sk = (t & 7) << 2;
            float4 v = *(const float4*)(u + (size_t)(row0 + sr) * DI_ + k0 + sk);
            ut[sr][sk] = v.x; ut[sr][sk+1] = v.y; ut[sr][sk+2] = v.z; ut[sr][sk+3] = v.w;
        }
        for (int i = t; i < 640; i += 256) {   // stage w tile 80x32
            int wr = i >> 3, wk = (i & 7) << 2;
            float4 v = *(const float4*)(xw + (size_t)wr * DI_ + k0 + wk);
            wt[wr][wk] = v.x; wt[wr][wk+1] = v.y; wt[wr][wk+2] = v.z; wt[wr][wk+3] = v.w;
        }
        __syncthreads();
        #pragma unroll 8
        for (int kk = 0; kk < 32; ++kk) {
            float a = ut[r][kk];
            #pragma unroll
            for (int c = 0; c < 10; ++c)
                acc[c] = fmaf(a, wt[j0 + c][kk], acc[c]);
        }
        __syncthreads();
    }
    size_t base = (size_t)(row0 + r) * 80 + j0;
    #pragma unroll
    for (int c = 0; c < 10; ++c)
        xdbl[base + c] = acc[c] + xb[j0 + c];
}

// ---------------------------------------------------------------------------
// dtwT[r][di] = dt_w[di][r]
// ---------------------------------------------------------------------------
__global__ __launch_bounds__(256)
void transpose_dtw(const float* __restrict__ dtw, float* __restrict__ dtwT)
{
    int idx = blockIdx.x * 256 + threadIdx.x;   // RR*DI
    int di  = idx & (DI_ - 1);
    int r   = idx >> 11;
    dtwT[(size_t)r * DI_ + di] = dtw[(size_t)di * RR + r];
}

// ---------------------------------------------------------------------------
// delta[M,DI] = softplus(xdbl[:, :64] @ dtwT + dt_b)
// ---------------------------------------------------------------------------
__global__ __launch_bounds__(256)
void delta_gemm(const float* __restrict__ xdbl, const float* __restrict__ dtwT,
                const float* __restrict__ dtb, float* __restrict__ delta)
{
    __shared__ float dl[16][64];
    const int t    = threadIdx.x;
    const int row0 = blockIdx.y * 16;
    const int col  = blockIdx.x * 256 + t;
    {   // stage delta_lr tile 16x64
        int sr = t >> 4, sk = (t & 15) << 2;
        float4 v = *(const float4*)(xdbl + (size_t)(row0 + sr) * 80 + sk);
        dl[sr][sk] = v.x; dl[sr][sk+1] = v.y; dl[sr][sk+2] = v.z; dl[sr][sk+3] = v.w;
    }
    __syncthreads();
    float acc[16] = {};
    for (int k = 0; k < 64; ++k) {
        float w = dtwT[(size_t)k * DI_ + col];
        #pragma unroll
        for (int rr = 0; rr < 16; ++rr)
            acc[rr] = fmaf(dl[rr][k], w, acc[rr]);
    }
    float bias = dtb[col];
    #pragma unroll
    for (int rr = 0; rr < 16; ++rr) {
        float x  = acc[rr] + bias;
        float sp = fmaxf(x, 0.f) + log1pf(__expf(-fabsf(x)));   // softplus
        delta[(size_t)(row0 + rr) * DI_ + col] = sp;
    }
}

// ---------------------------------------------------------------------------
// Scan pass A: per (b, chunk, di) compute P[n]=prod(dA), S[n]=scan-from-zero
// ---------------------------------------------------------------------------
__global__ __launch_bounds__(256)
void scanA(const float* __restrict__ delta, const float* __restrict__ u,
           const float* __restrict__ xdbl, const float* __restrict__ A_log,
           float* __restrict__ Pbuf, float* __restrict__ Sbuf)
{
    const int tid  = blockIdx.x * 256 + threadIdx.x;   // B*NC*DI
    const int di   = tid & (DI_ - 1);
    const int rest = tid >> 11;
    const int ch   = rest & (NC - 1);
    const int b    = rest >> 5;
    float A2[NS];
    {
        const float4* ap = (const float4*)(A_log + (size_t)di * NS);
        #pragma unroll
        for (int q = 0; q < 4; ++q) {
            float4 v = ap[q];
            A2[q*4+0] = -__expf(v.x) * 1.44269504f;   // A * log2(e): exp(d*A)=exp2(d*A2)
            A2[q*4+1] = -__expf(v.y) * 1.44269504f;
            A2[q*4+2] = -__expf(v.z) * 1.44269504f;
            A2[q*4+3] = -__expf(v.w) * 1.44269504f;
        }
    }
    float c[NS], P[NS];
    #pragma unroll
    for (int n = 0; n < NS; ++n) { c[n] = 0.f; P[n] = 1.f; }
    const size_t l0 = (size_t)b * L_ + (size_t)ch * CL;
    const float* dp = delta + l0 * DI_ + di;
    const float* up = u     + l0 * DI_ + di;
    const float* xp = xdbl  + l0 * 80 + RR;
    for (int l = 0; l < CL; ++l) {
        float dlt = dp[(size_t)l * DI_];
        float du  = dlt * up[(size_t)l * DI_];
        const float4* bp = (const float4*)(xp + (size_t)l * 80);
        #pragma unroll
        for (int q = 0; q < 4; ++q) {
            float4 bv = bp[q];
            float bn_[4] = {bv.x, bv.y, bv.z, bv.w};
            #pragma unroll
            for (int j = 0; j < 4; ++j) {
                int   n = q * 4 + j;
                float a = exp2f(dlt * A2[n]);
                c[n] = fmaf(a, c[n], du * bn_[j]);
                P[n] *= a;
            }
        }
    }
    float4* Pp = (float4*)(Pbuf + (size_t)tid * NS);
    float4* Sp = (float4*)(Sbuf + (size_t)tid * NS);
    #pragma unroll
    for (int q = 0; q < 4; ++q) {
        Pp[q] = make_float4(P[q*4], P[q*4+1], P[q*4+2], P[q*4+3]);
        Sp[q] = make_float4(c[q*4], c[q*4+1], c[q*4+2], c[q*4+3]);
    }
}

// ---------------------------------------------------------------------------
// Scan pass B: combine chunk summaries -> start state per chunk
// ---------------------------------------------------------------------------
__global__ __launch_bounds__(256)
void scanB(const float* __restrict__ Pbuf, const float* __restrict__ Sbuf,
           float* __restrict__ start)
{
    const int tid = blockIdx.x * 256 + threadIdx.x;   // B*DI*NS
    const int n   = tid & (NS - 1);
    const int di  = (tid >> 4) & (DI_ - 1);
    const int b   = tid >> 15;
    float c = 0.f;
    for (int ch = 0; ch < NC; ++ch) {
        size_t idx = ((size_t)(b * NC + ch) * DI_ + di) * NS + n;
        start[idx] = c;
        c = fmaf(Pbuf[idx], c, Sbuf[idx]);
    }
}

// ---------------------------------------------------------------------------
// Scan pass C: replay chunks from correct start state, y written in-place
// over delta buffer:  y = sum_n(c_n) + u*D
// ---------------------------------------------------------------------------
__global__ __launch_bounds__(256)
void scanC(float* __restrict__ dy, const float* __restrict__ u,
           const float* __restrict__ xdbl, const float* __restrict__ A_log,
           const float* __restrict__ Dp, const float* __restrict__ start)
{
    const int tid  = blockIdx.x * 256 + threadIdx.x;
    const int di   = tid & (DI_ - 1);
    const int rest = tid >> 11;
    const int ch   = rest & (NC - 1);
    const int b    = rest >> 5;
    float A2[NS];
    {
        const float4* ap = (const float4*)(A_log + (size_t)di * NS);
        #pragma unroll
        for (int q = 0; q < 4; ++q) {
            float4 v = ap[q];
            A2[q*4+0] = -__expf(v.x) * 1.44269504f;
            A2[q*4+1] = -__expf(v.y) * 1.44269504f;
            A2[q*4+2] = -__expf(v.z) * 1.44269504f;
            A2[q*4+3] = -__expf(v.w) * 1.44269504f;
        }
    }
    float c[NS];
    {
        const float4* sp = (const float4*)(start + (size_t)tid * NS);
        #pragma unroll
        for (int q = 0; q < 4; ++q) {
            float4 v = sp[q];
            c[q*4+0] = v.x; c[q*4+1] = v.y; c[q*4+2] = v.z; c[q*4+3] = v.w;
        }
    }
    const float Dpar = Dp[di];
    const size_t l0 = (size_t)b * L_ + (size_t)ch * CL;
    float*       dp = dy   + l0 * DI_ + di;
    const float* up = u    + l0 * DI_ + di;
    const float* xp = xdbl + l0 * 80 + RR;
    for (int l = 0; l < CL; ++l) {
        float dlt = dp[(size_t)l * DI_];
        float uu  = up[(size_t)l * DI_];
        float du  = dlt * uu;
        const float4* bp = (const float4*)(xp + (size_t)l * 80);
        float sum = 0.f;
        #pragma unroll
        for (int q = 0; q < 4; ++q) {
            float4 bv = bp[q];
            float bn_[4] = {bv.x, bv.y, bv.z, bv.w};
            #pragma unroll
            for (int j = 0; j < 4; ++j) {
                int   n = q * 4 + j;
                float a = exp2f(dlt * A2[n]);
                c[n] = fmaf(a, c[n], du * bn_[j]);
                sum += c[n];
            }
        }
        dp[(size_t)l * DI_] = sum + uu * Dpar;   // overwrite delta with y
    }
}

// ---------------------------------------------------------------------------
extern "C" void kernel_launch(void* const* d_in, const int* in_sizes, int n_in,
                              void* d_out, int out_size, void* d_ws, size_t ws_size,
                              hipStream_t stream)
{
    const float* x      = (const float*)d_in[0];
    const float* in_w   = (const float*)d_in[1];
    const float* in_b   = (const float*)d_in[2];
    const float* conv_w = (const float*)d_in[3];
    const float* conv_b = (const float*)d_in[4];
    const float* xpw    = (const float*)d_in[5];
    const float* xpb    = (const float*)d_in[6];
    const float* dt_w   = (const float*)d_in[7];
    const float* dt_b   = (const float*)d_in[8];
    const float* A_log  = (const float*)d_in[9];
    const float* Dpar   = (const float*)d_in[10];
    const float* out_w  = (const float*)d_in[11];
    const float* out_b  = (const float*)d_in[12];
    float*       out    = (float*)d_out;

    char* ws  = (char*)d_ws;
    size_t off = 0;
    auto alloc = [&](size_t bytes) {
        void* p = ws + off; off = (off + bytes + 255) & ~(size_t)255; return p;
    };
    float* u_    = (float*)alloc((size_t)MM * DI_ * 4);
    float* h_    = (float*)alloc((size_t)MM * DI_ * 4);   // h -> delta -> y (in place)
    float* xdbl  = (float*)alloc((size_t)MM * 80 * 4);
    float* dtwT  = (float*)alloc((size_t)RR * DI_ * 4);
    float* Pbuf  = (float*)alloc((size_t)B_ * NC * DI_ * NS * 4);
    float* Sbuf  = (float*)alloc((size_t)B_ * NC * DI_ * NS * 4);
    float* stbuf = (float*)alloc((size_t)B_ * NC * DI_ * NS * 4);

    // 1. h = x @ in_w^T + in_b            [4096 x 2048], K=1024
    gemm64<<<dim3(DI_ / 64, MM / 64), 256, 0, stream>>>(x, in_w, in_b, h_, MM, DI_, D_);
    // 2. u = silu(conv3(h) + conv_b)
    conv_silu<<<(MM * DI_) / 256, 256, 0, stream>>>(h_, conv_w, conv_b, u_);
    // 3. x_dbl = u @ x_proj_w^T + x_proj_b   [4096 x 80], K=2048
    xproj<<<MM / 32, 256, 0, stream>>>(u_, xpw, xpb, xdbl);
    // 4. dt_w transpose
    transpose_dtw<<<(RR * DI_) / 256, 256, 0, stream>>>(dt_w, dtwT);
    // 5. delta = softplus(delta_lr @ dt_w^T + dt_b)  -> into h_ buffer
    delta_gemm<<<dim3(DI_ / 256, MM / 16), 256, 0, stream>>>(xdbl, dtwT, dt_b, h_);
    // 6-8. chunked selective scan; y replaces delta in h_
    scanA<<<(B_ * NC * DI_) / 256, 256, 0, stream>>>(h_, u_, xdbl, A_log, Pbuf, Sbuf);
    scanB<<<(B_ * DI_ * NS) / 256, 256, 0, stream>>>(Pbuf, Sbuf, stbuf);
    scanC<<<(B_ * NC * DI_) / 256, 256, 0, stream>>>(h_, u_, xdbl, A_log, Dpar, stbuf);
    // 9. out = y @ out_w^T + out_b        [4096 x 1024], K=2048
    gemm64<<<dim3(D_ / 64, MM / 64), 256, 0, stream>>>(h_, out_w, out_b, out, MM, D_, DI_);
}

// Round 2
// 664.760 us; speedup vs baseline: 1.5840x; 1.5840x over previous
//
#include <hip/hip_runtime.h>
#include <hip/hip_bf16.h>

#define B_  2
#define L_  2048
#define D_  1024
#define DI_ 2048
#define NS  16
#define RR  64
#define MM  (B_*L_)      // 4096 rows
#define NC  32           // scan chunks
#define CL  (L_/NC)      // 64 steps per chunk
#define XKS 8            // xproj split-K slices (K-slice = 256)

typedef __attribute__((ext_vector_type(8))) short bf16x8;
typedef __attribute__((ext_vector_type(4))) float f32x4;

__device__ inline ushort f2bf_rn(float f) {
    union { float f; unsigned u; } v; v.f = f;
    unsigned r = v.u + 0x7FFF + ((v.u >> 16) & 1);
    return (ushort)(r >> 16);
}
__device__ inline float bf2f(ushort h) {
    union { unsigned u; float f; } v; v.u = ((unsigned)h) << 16;
    return v.f;
}

// ---------------------------------------------------------------------------
// C[M,N] = A[M,K] @ W[N,K]^T + bias[N]  via bf16x3 MFMA (error ~2^-16 rel)
// tile 128x128, BK=32, 256 thr = 4 waves, each wave 64x64 (4x4 frags 16x16)
// LDS row layout: cols [0..31]=hi, [32..63]=lo, stride 72 ushorts (144B, %16=0)
// ---------------------------------------------------------------------------
__global__ __launch_bounds__(256, 2)
void gemm_mfma(const float* __restrict__ A, const float* __restrict__ W,
               const float* __restrict__ bias, float* __restrict__ C,
               int M, int N, int K)
{
    __shared__ ushort As[128][72];
    __shared__ ushort Ws[128][72];
    const int t    = threadIdx.x;
    const int bm   = blockIdx.y * 128, bn = blockIdx.x * 128;
    const int lane = t & 63, wv = t >> 6;
    const int wr   = (wv >> 1) * 64, wc = (wv & 1) * 64;
    const int l16  = lane & 15;
    const int lko  = (lane >> 4) * 8;          // k-base of this lane's fragment
    const int srow = t >> 3;                   // staging row 0..31
    const int sk4  = (t & 7) * 4;              // staging k 0,4,..,28

    f32x4 acc[4][4];
    #pragma unroll
    for (int i = 0; i < 4; ++i)
        #pragma unroll
        for (int j = 0; j < 4; ++j)
            acc[i][j] = (f32x4){0.f, 0.f, 0.f, 0.f};

    for (int k0 = 0; k0 < K; k0 += 32) {
        #pragma unroll
        for (int i = 0; i < 4; ++i) {
            int row = srow + 32 * i;
            float4 va = *(const float4*)(A + (size_t)(bm + row) * K + k0 + sk4);
            float4 vw = *(const float4*)(W + (size_t)(bn + row) * K + k0 + sk4);
            float af[4] = {va.x, va.y, va.z, va.w};
            float wf[4] = {vw.x, vw.y, vw.z, vw.w};
            ushort ah[4], al[4], wh[4], wl[4];
            #pragma unroll
            for (int j = 0; j < 4; ++j) {
                ah[j] = f2bf_rn(af[j]); al[j] = f2bf_rn(af[j] - bf2f(ah[j]));
                wh[j] = f2bf_rn(wf[j]); wl[j] = f2bf_rn(wf[j] - bf2f(wh[j]));
            }
            *(ushort4*)&As[row][sk4]      = make_ushort4(ah[0], ah[1], ah[2], ah[3]);
            *(ushort4*)&As[row][32 + sk4] = make_ushort4(al[0], al[1], al[2], al[3]);
            *(ushort4*)&Ws[row][sk4]      = make_ushort4(wh[0], wh[1], wh[2], wh[3]);
            *(ushort4*)&Ws[row][32 + sk4] = make_ushort4(wl[0], wl[1], wl[2], wl[3]);
        }
        __syncthreads();
        bf16x8 fah[4], fal[4], fbh[4], fbl[4];
        #pragma unroll
        for (int mi = 0; mi < 4; ++mi) {
            int m = wr + mi * 16 + l16;
            fah[mi] = *(const bf16x8*)&As[m][lko];
            fal[mi] = *(const bf16x8*)&As[m][32 + lko];
        }
        #pragma unroll
        for (int nj = 0; nj < 4; ++nj) {
            int n = wc + nj * 16 + l16;
            fbh[nj] = *(const bf16x8*)&Ws[n][lko];
            fbl[nj] = *(const bf16x8*)&Ws[n][32 + lko];
        }
        #pragma unroll
        for (int mi = 0; mi < 4; ++mi)
            #pragma unroll
            for (int nj = 0; nj < 4; ++nj) {
                acc[mi][nj] = __builtin_amdgcn_mfma_f32_16x16x32_bf16(fah[mi], fbh[nj], acc[mi][nj], 0, 0, 0);
                acc[mi][nj] = __builtin_amdgcn_mfma_f32_16x16x32_bf16(fah[mi], fbl[nj], acc[mi][nj], 0, 0, 0);
                acc[mi][nj] = __builtin_amdgcn_mfma_f32_16x16x32_bf16(fal[mi], fbh[nj], acc[mi][nj], 0, 0, 0);
            }
        __syncthreads();
    }
    // C/D layout: col = lane&15, row = (lane>>4)*4 + reg  [m89-verified]
    #pragma unroll
    for (int nj = 0; nj < 4; ++nj) {
        int col = bn + wc + nj * 16 + l16;
        float bb = bias[col];
        #pragma unroll
        for (int mi = 0; mi < 4; ++mi) {
            int row0 = bm + wr + mi * 16 + (lane >> 4) * 4;
            #pragma unroll
            for (int r = 0; r < 4; ++r)
                C[(size_t)(row0 + r) * N + col] = acc[mi][nj][r] + bb;
        }
    }
}

// ---------------------------------------------------------------------------
// u = silu(depthwise_conv3(h) + conv_b)
// ---------------------------------------------------------------------------
__global__ __launch_bounds__(256)
void conv_silu(const float* __restrict__ h, const float* __restrict__ cw,
               const float* __restrict__ cb, float* __restrict__ u)
{
    size_t idx = (size_t)blockIdx.x * 256 + threadIdx.x;   // B*L*DI
    int    di  = idx & (DI_ - 1);
    size_t bl  = idx >> 11;            // /DI_
    int    l   = (int)(bl & (L_ - 1));
    float s = cb[di] + h[idx] * cw[di * 3 + 1];
    if (l > 0)      s += h[idx - DI_] * cw[di * 3 + 0];
    if (l < L_ - 1) s += h[idx + DI_] * cw[di * 3 + 2];
    u[idx] = s / (1.f + __expf(-s));   // silu
}

// ---------------------------------------------------------------------------
// xproj stage A: partial[s][m][c] = sum_{k in slice s} u[m][k]*xw[c][k]
// grid (M/32, XKS); block 256. rows r2,r2+16 ; cols cg*5..+4 per thread
// ---------------------------------------------------------------------------
__global__ __launch_bounds__(256)
void xprojA(const float* __restrict__ u, const float* __restrict__ xw,
            float* __restrict__ part)
{
    __shared__ float ut[32][132];
    __shared__ float wt[80][132];
    const int t  = threadIdx.x;
    const int bm = blockIdx.x * 32;
    const int ks = blockIdx.y;
    const int r2 = t & 15, cg = t >> 4;
    float acc[2][5] = {};
    for (int ch = 0; ch < 2; ++ch) {
        const int kb = ks * 256 + ch * 128;
        {   // stage u tile 32x128
            int sr = t >> 3, k4 = (t & 7) * 4;
            #pragma unroll
            for (int i = 0; i < 4; ++i) {
                float4 v = *(const float4*)(u + (size_t)(bm + sr) * DI_ + kb + k4 + 32 * i);
                ut[sr][k4 + 32*i + 0] = v.x; ut[sr][k4 + 32*i + 1] = v.y;
                ut[sr][k4 + 32*i + 2] = v.z; ut[sr][k4 + 32*i + 3] = v.w;
            }
        }
        #pragma unroll
        for (int i = 0; i < 10; ++i) {   // stage w tile 80x128
            int idx = t + 256 * i;
            int wrow = idx >> 5, k4 = (idx & 31) * 4;
            float4 v = *(const float4*)(xw + (size_t)wrow * DI_ + kb + k4);
            wt[wrow][k4 + 0] = v.x; wt[wrow][k4 + 1] = v.y;
            wt[wrow][k4 + 2] = v.z; wt[wrow][k4 + 3] = v.w;
        }
        __syncthreads();
        for (int k = 0; k < 128; k += 4) {
            float4 u0 = *(const float4*)&ut[r2][k];
            float4 u1 = *(const float4*)&ut[r2 + 16][k];
            #pragma unroll
            for (int c = 0; c < 5; ++c) {
                float4 wv = *(const float4*)&wt[cg * 5 + c][k];
                acc[0][c] = fmaf(u0.x, wv.x, fmaf(u0.y, wv.y, fmaf(u0.z, wv.z, fmaf(u0.w, wv.w, acc[0][c]))));
                acc[1][c] = fmaf(u1.x, wv.x, fmaf(u1.y, wv.y, fmaf(u1.z, wv.z, fmaf(u1.w, wv.w, acc[1][c]))));
            }
        }
        __syncthreads();
    }
    size_t b0 = ((size_t)ks * MM + bm + r2) * 80 + cg * 5;
    size_t b1 = ((size_t)ks * MM + bm + r2 + 16) * 80 + cg * 5;
    #pragma unroll
    for (int c = 0; c < 5; ++c) { part[b0 + c] = acc[0][c]; part[b1 + c] = acc[1][c]; }
}

// ---------------------------------------------------------------------------
// xproj stage B: xdbl[m][c] = bias[c] + sum_s partial[s][m][c]
// ---------------------------------------------------------------------------
__global__ __launch_bounds__(256)
void xprojB(const float* __restrict__ part, const float* __restrict__ xpb,
            float* __restrict__ xdbl)
{
    int idx = blockIdx.x * 256 + threadIdx.x;   // MM*80
    int c = idx % 80;
    float s = xpb[c];
    #pragma unroll
    for (int sl = 0; sl < XKS; ++sl)
        s += part[(size_t)sl * (MM * 80) + idx];
    xdbl[idx] = s;
}

// ---------------------------------------------------------------------------
// dtwT[r][di] = dt_w[di][r]
// ---------------------------------------------------------------------------
__global__ __launch_bounds__(256)
void transpose_dtw(const float* __restrict__ dtw, float* __restrict__ dtwT)
{
    int idx = blockIdx.x * 256 + threadIdx.x;   // RR*DI
    int di  = idx & (DI_ - 1);
    int r   = idx >> 11;
    dtwT[(size_t)r * DI_ + di] = dtw[(size_t)di * RR + r];
}

// ---------------------------------------------------------------------------
// delta[M,DI] = softplus(xdbl[:, :64] @ dtwT + dt_b)
// ---------------------------------------------------------------------------
__global__ __launch_bounds__(256)
void delta_gemm(const float* __restrict__ xdbl, const float* __restrict__ dtwT,
                const float* __restrict__ dtb, float* __restrict__ delta)
{
    __shared__ float dl[16][64];
    const int t    = threadIdx.x;
    const int row0 = blockIdx.y * 16;
    const int col  = blockIdx.x * 256 + t;
    {   // stage delta_lr tile 16x64
        int sr = t >> 4, sk = (t & 15) << 2;
        float4 v = *(const float4*)(xdbl + (size_t)(row0 + sr) * 80 + sk);
        dl[sr][sk] = v.x; dl[sr][sk+1] = v.y; dl[sr][sk+2] = v.z; dl[sr][sk+3] = v.w;
    }
    __syncthreads();
    float acc[16] = {};
    for (int k = 0; k < 64; ++k) {
        float w = dtwT[(size_t)k * DI_ + col];
        #pragma unroll
        for (int rr = 0; rr < 16; ++rr)
            acc[rr] = fmaf(dl[rr][k], w, acc[rr]);
    }
    float bias = dtb[col];
    #pragma unroll
    for (int rr = 0; rr < 16; ++rr) {
        float x  = acc[rr] + bias;
        float sp = fmaxf(x, 0.f) + log1pf(__expf(-fabsf(x)));   // softplus
        delta[(size_t)(row0 + rr) * DI_ + col] = sp;
    }
}

// ---------------------------------------------------------------------------
// Scan pass A: per (b, chunk, di) compute P[n]=prod(dA), S[n]=scan-from-zero
// ---------------------------------------------------------------------------
__global__ __launch_bounds__(256)
void scanA(const float* __restrict__ delta, const float* __restrict__ u,
           const float* __restrict__ xdbl, const float* __restrict__ A_log,
           float* __restrict__ Pbuf, float* __restrict__ Sbuf)
{
    const int tid  = blockIdx.x * 256 + threadIdx.x;   // B*NC*DI
    const int di   = tid & (DI_ - 1);
    const int rest = tid >> 11;
    const int ch   = rest & (NC - 1);
    const int b    = rest >> 5;
    float A2[NS];
    {
        const float4* ap = (const float4*)(A_log + (size_t)di * NS);
        #pragma unroll
        for (int q = 0; q < 4; ++q) {
            float4 v = ap[q];
            A2[q*4+0] = -__expf(v.x) * 1.44269504f;
            A2[q*4+1] = -__expf(v.y) * 1.44269504f;
            A2[q*4+2] = -__expf(v.z) * 1.44269504f;
            A2[q*4+3] = -__expf(v.w) * 1.44269504f;
        }
    }
    float c[NS], P[NS];
    #pragma unroll
    for (int n = 0; n < NS; ++n) { c[n] = 0.f; P[n] = 1.f; }
    const size_t l0 = (size_t)b * L_ + (size_t)ch * CL;
    const float* dp = delta + l0 * DI_ + di;
    const float* up = u     + l0 * DI_ + di;
    const float* xp = xdbl  + l0 * 80 + RR;
    for (int l = 0; l < CL; ++l) {
        float dlt = dp[(size_t)l * DI_];
        float du  = dlt * up[(size_t)l * DI_];
        const float4* bp = (const float4*)(xp + (size_t)l * 80);
        #pragma unroll
        for (int q = 0; q < 4; ++q) {
            float4 bv = bp[q];
            float bn_[4] = {bv.x, bv.y, bv.z, bv.w};
            #pragma unroll
            for (int j = 0; j < 4; ++j) {
                int   n = q * 4 + j;
                float a = exp2f(dlt * A2[n]);
                c[n] = fmaf(a, c[n], du * bn_[j]);
                P[n] *= a;
            }
        }
    }
    float4* Pp = (float4*)(Pbuf + (size_t)tid * NS);
    float4* Sp = (float4*)(Sbuf + (size_t)tid * NS);
    #pragma unroll
    for (int q = 0; q < 4; ++q) {
        Pp[q] = make_float4(P[q*4], P[q*4+1], P[q*4+2], P[q*4+3]);
        Sp[q] = make_float4(c[q*4], c[q*4+1], c[q*4+2], c[q*4+3]);
    }
}

// ---------------------------------------------------------------------------
// Scan pass B: combine chunk summaries -> start state per chunk
// ---------------------------------------------------------------------------
__global__ __launch_bounds__(256)
void scanB(const float* __restrict__ Pbuf, const float* __restrict__ Sbuf,
           float* __restrict__ start)
{
    const int tid = blockIdx.x * 256 + threadIdx.x;   // B*DI*NS
    const int n   = tid & (NS - 1);
    const int di  = (tid >> 4) & (DI_ - 1);
    const int b   = tid >> 15;
    float c = 0.f;
    for (int ch = 0; ch < NC; ++ch) {
        size_t idx = ((size_t)(b * NC + ch) * DI_ + di) * NS + n;
        start[idx] = c;
        c = fmaf(Pbuf[idx], c, Sbuf[idx]);
    }
}

// ---------------------------------------------------------------------------
// Scan pass C: replay chunks from start state; y overwrites delta buffer
// ---------------------------------------------------------------------------
__global__ __launch_bounds__(256)
void scanC(float* __restrict__ dy, const float* __restrict__ u,
           const float* __restrict__ xdbl, const float* __restrict__ A_log,
           const float* __restrict__ Dp, const float* __restrict__ start)
{
    const int tid  = blockIdx.x * 256 + threadIdx.x;
    const int di   = tid & (DI_ - 1);
    const int rest = tid >> 11;
    const int ch   = rest & (NC - 1);
    const int b    = rest >> 5;
    float A2[NS];
    {
        const float4* ap = (const float4*)(A_log + (size_t)di * NS);
        #pragma unroll
        for (int q = 0; q < 4; ++q) {
            float4 v = ap[q];
            A2[q*4+0] = -__expf(v.x) * 1.44269504f;
            A2[q*4+1] = -__expf(v.y) * 1.44269504f;
            A2[q*4+2] = -__expf(v.z) * 1.44269504f;
            A2[q*4+3] = -__expf(v.w) * 1.44269504f;
        }
    }
    float c[NS];
    {
        const float4* sp = (const float4*)(start + (size_t)tid * NS);
        #pragma unroll
        for (int q = 0; q < 4; ++q) {
            float4 v = sp[q];
            c[q*4+0] = v.x; c[q*4+1] = v.y; c[q*4+2] = v.z; c[q*4+3] = v.w;
        }
    }
    const float Dpar = Dp[di];
    const size_t l0 = (size_t)b * L_ + (size_t)ch * CL;
    float*       dp = dy   + l0 * DI_ + di;
    const float* up = u    + l0 * DI_ + di;
    const float* xp = xdbl + l0 * 80 + RR;
    for (int l = 0; l < CL; ++l) {
        float dlt = dp[(size_t)l * DI_];
        float uu  = up[(size_t)l * DI_];
        float du  = dlt * uu;
        const float4* bp = (const float4*)(xp + (size_t)l * 80);
        float sum = 0.f;
        #pragma unroll
        for (int q = 0; q < 4; ++q) {
            float4 bv = bp[q];
            float bn_[4] = {bv.x, bv.y, bv.z, bv.w};
            #pragma unroll
            for (int j = 0; j < 4; ++j) {
                int   n = q * 4 + j;
                float a = exp2f(dlt * A2[n]);
                c[n] = fmaf(a, c[n], du * bn_[j]);
                sum += c[n];
            }
        }
        dp[(size_t)l * DI_] = sum + uu * Dpar;
    }
}

// ---------------------------------------------------------------------------
extern "C" void kernel_launch(void* const* d_in, const int* in_sizes, int n_in,
                              void* d_out, int out_size, void* d_ws, size_t ws_size,
                              hipStream_t stream)
{
    const float* x      = (const float*)d_in[0];
    const float* in_w   = (const float*)d_in[1];
    const float* in_b   = (const float*)d_in[2];
    const float* conv_w = (const float*)d_in[3];
    const float* conv_b = (const float*)d_in[4];
    const float* xpw    = (const float*)d_in[5];
    const float* xpb    = (const float*)d_in[6];
    const float* dt_w   = (const float*)d_in[7];
    const float* dt_b   = (const float*)d_in[8];
    const float* A_log  = (const float*)d_in[9];
    const float* Dpar   = (const float*)d_in[10];
    const float* out_w  = (const float*)d_in[11];
    const float* out_b  = (const float*)d_in[12];
    float*       out    = (float*)d_out;

    char* ws  = (char*)d_ws;
    size_t off = 0;
    auto alloc = [&](size_t bytes) {
        void* p = ws + off; off = (off + bytes + 255) & ~(size_t)255; return p;
    };
    float* u_    = (float*)alloc((size_t)MM * DI_ * 4);
    float* h_    = (float*)alloc((size_t)MM * DI_ * 4);   // h -> delta -> y (in place)
    float* xdbl  = (float*)alloc((size_t)MM * 80 * 4);
    float* dtwT  = (float*)alloc((size_t)RR * DI_ * 4);
    // scr: xpart (XKS*MM*80*4 = 10.5 MB) dead after xprojB, then reused as P/S/start
    const size_t pse = (size_t)B_ * NC * DI_ * NS;        // elements per scan buffer
    float* scr   = (float*)alloc(3 * pse * 4);            // 25.2 MB >= 10.5 MB
    float* xpart = scr;
    float* Pbuf  = scr;
    float* Sbuf  = scr + pse;
    float* stbuf = scr + 2 * pse;

    // 1. h = x @ in_w^T + in_b            [4096 x 2048], K=1024
    gemm_mfma<<<dim3(DI_ / 128, MM / 128), 256, 0, stream>>>(x, in_w, in_b, h_, MM, DI_, D_);
    // 2. u = silu(conv3(h) + conv_b)
    conv_silu<<<(MM * DI_) / 256, 256, 0, stream>>>(h_, conv_w, conv_b, u_);
    // 3. x_dbl = u @ x_proj_w^T + x_proj_b  (split-K two-stage)
    xprojA<<<dim3(MM / 32, XKS), 256, 0, stream>>>(u_, xpw, xpart);
    xprojB<<<(MM * 80) / 256, 256, 0, stream>>>(xpart, xpb, xdbl);
    // 4. dt_w transpose
    transpose_dtw<<<(RR * DI_) / 256, 256, 0, stream>>>(dt_w, dtwT);
    // 5. delta = softplus(delta_lr @ dt_w^T + dt_b)  -> into h_ buffer
    delta_gemm<<<dim3(DI_ / 256, MM / 16), 256, 0, stream>>>(xdbl, dtwT, dt_b, h_);
    // 6-8. chunked selective scan; y replaces delta in h_
    scanA<<<(B_ * NC * DI_) / 256, 256, 0, stream>>>(h_, u_, xdbl, A_log, Pbuf, Sbuf);
    scanB<<<(B_ * DI_ * NS) / 256, 256, 0, stream>>>(Pbuf, Sbuf, stbuf);
    scanC<<<(B_ * NC * DI_) / 256, 256, 0, stream>>>(h_, u_, xdbl, A_log, Dpar, stbuf);
    // 9. out = y @ out_w^T + out_b        [4096 x 1024], K=2048
    gemm_mfma<<<dim3(D_ / 128, MM / 128), 256, 0, stream>>>(h_, out_w, out_b, out, MM, D_, DI_);
}

// Round 3
// 454.356 us; speedup vs baseline: 2.3175x; 1.4631x over previous
//
#include <hip/hip_runtime.h>

#define B_  2
#define L_  2048
#define D_  1024
#define DI_ 2048
#define NS  16
#define RR  64
#define MM  (B_*L_)      // 4096 rows
#define NC  32           // scan chunks
#define CL  (L_/NC)      // 64 steps per chunk
#define XKS 8            // xproj split-K slices

typedef __attribute__((ext_vector_type(8))) short bf16x8;
typedef __attribute__((ext_vector_type(4))) float f32x4;

__device__ __forceinline__ ushort f2bf_rn(float f) {
    union { float f; unsigned u; } v; v.f = f;
    unsigned r = v.u + 0x7FFF + ((v.u >> 16) & 1);
    return (ushort)(r >> 16);
}
__device__ __forceinline__ float bf2f(ushort h) {
    union { unsigned u; float f; } v; v.u = ((unsigned)h) << 16;
    return v.f;
}
__device__ __forceinline__ void gload_lds16(const ushort* g, ushort* l) {
    __builtin_amdgcn_global_load_lds(
        (const __attribute__((address_space(1))) void*)(g),
        (__attribute__((address_space(3))) void*)(l), 16, 0, 0);
}

// ---------------------------------------------------------------------------
// cvt: fp32 -> bf16 hi/lo pair (elementwise, n multiple of 4)
// ---------------------------------------------------------------------------
__global__ __launch_bounds__(256)
void cvt_hilo(const float* __restrict__ in, ushort* __restrict__ hi,
              ushort* __restrict__ lo, int n4)
{
    int i = blockIdx.x * 256 + threadIdx.x;
    if (i >= n4) return;
    float4 v = ((const float4*)in)[i];
    ushort4 h, l;
    h.x = f2bf_rn(v.x); l.x = f2bf_rn(v.x - bf2f(h.x));
    h.y = f2bf_rn(v.y); l.y = f2bf_rn(v.y - bf2f(h.y));
    h.z = f2bf_rn(v.z); l.z = f2bf_rn(v.z - bf2f(h.z));
    h.w = f2bf_rn(v.w); l.w = f2bf_rn(v.w - bf2f(h.w));
    ((ushort4*)hi)[i] = h; ((ushort4*)lo)[i] = l;
}

// ---------------------------------------------------------------------------
// C[M,N] = A@W^T (+bias) via bf16x3: hi*hi + hi*lo + lo*hi, fp32 accum.
// Tile 128x128, BK=32, 256 thr = 4 waves, each wave 64x64 (4x4 16x16 frags).
// Staging: global_load_lds w=16, linear LDS dest, swizzle via global source
// slot (i&3)^((i>>3)&3); reads use slot (lane>>4)^((l16>>1)&3)  [rule 21].
// gridDim.z = split-K; partial z writes C + z*MM*N.
// ---------------------------------------------------------------------------
__global__ __launch_bounds__(256, 2)
void gemm_bf16x3(const ushort* __restrict__ Ah, const ushort* __restrict__ Al,
                 const ushort* __restrict__ Bh, const ushort* __restrict__ Bl,
                 const float* __restrict__ bias, float* __restrict__ C,
                 int lda, int N, int kPerSplit)
{
    __shared__ ushort sAh[128*32], sAl[128*32], sBh[128*32], sBl[128*32];
    const int t    = threadIdx.x;
    const int bm   = blockIdx.y * 128, bn = blockIdx.x * 128;
    const int lane = t & 63, w = t >> 6;
    const int wr   = (w >> 1) * 64, wc = (w & 1) * 64;
    const int l16  = lane & 15;
    const int kbeg = blockIdx.z * kPerSplit;
    const int kend = kbeg + kPerSplit;
    C += (size_t)blockIdx.z * MM * N;

    // --- staging addresses (lane i of wave w stages rows 32w+16c+i/4) ---
    const int srow  = lane >> 2;
    const int sslot = (lane & 3) ^ ((lane >> 3) & 3);   // inverse-swizzled source
    const int r0 = 32 * w + srow, r1 = r0 + 16;
    const ushort* gAh0 = Ah + (size_t)(bm + r0) * lda + sslot * 8 + kbeg;
    const ushort* gAh1 = Ah + (size_t)(bm + r1) * lda + sslot * 8 + kbeg;
    const ushort* gAl0 = Al + (size_t)(bm + r0) * lda + sslot * 8 + kbeg;
    const ushort* gAl1 = Al + (size_t)(bm + r1) * lda + sslot * 8 + kbeg;
    const ushort* gBh0 = Bh + (size_t)(bn + r0) * lda + sslot * 8 + kbeg;
    const ushort* gBh1 = Bh + (size_t)(bn + r1) * lda + sslot * 8 + kbeg;
    const ushort* gBl0 = Bl + (size_t)(bn + r0) * lda + sslot * 8 + kbeg;
    const ushort* gBl1 = Bl + (size_t)(bn + r1) * lda + sslot * 8 + kbeg;
    ushort* lA0 = sAh + 1024 * w;          // chunk bases (wave-uniform)
    ushort* lA1 = sAh + 1024 * w + 512;
    ushort* lAl0 = sAl + 1024 * w, *lAl1 = sAl + 1024 * w + 512;
    ushort* lB0 = sBh + 1024 * w, *lB1 = sBh + 1024 * w + 512;
    ushort* lBl0 = sBl + 1024 * w, *lBl1 = sBl + 1024 * w + 512;

    // --- fragment read offsets (swizzled) ---
    const int swz = ((lane >> 4) ^ ((l16 >> 1) & 3));   // 16B slot
    const int offA = (wr + l16) * 32 + swz * 8;         // + mi*512
    const int offB = (wc + l16) * 32 + swz * 8;         // + nj*512

    f32x4 acc[4][4];
    #pragma unroll
    for (int i = 0; i < 4; ++i)
        #pragma unroll
        for (int j = 0; j < 4; ++j)
            acc[i][j] = (f32x4){0.f, 0.f, 0.f, 0.f};

    for (int k0 = 0; k0 < kPerSplit; k0 += 32) {
        gload_lds16(gAh0 + k0, lA0);  gload_lds16(gAh1 + k0, lA1);
        gload_lds16(gAl0 + k0, lAl0); gload_lds16(gAl1 + k0, lAl1);
        gload_lds16(gBh0 + k0, lB0);  gload_lds16(gBh1 + k0, lB1);
        gload_lds16(gBl0 + k0, lBl0); gload_lds16(gBl1 + k0, lBl1);
        __syncthreads();
        bf16x8 fbh[4], fbl[4];
        #pragma unroll
        for (int nj = 0; nj < 4; ++nj) {
            fbh[nj] = *(const bf16x8*)(sBh + offB + nj * 512);
            fbl[nj] = *(const bf16x8*)(sBl + offB + nj * 512);
        }
        #pragma unroll
        for (int mi = 0; mi < 4; ++mi) {
            bf16x8 fah = *(const bf16x8*)(sAh + offA + mi * 512);
            bf16x8 fal = *(const bf16x8*)(sAl + offA + mi * 512);
            #pragma unroll
            for (int nj = 0; nj < 4; ++nj) {
                acc[mi][nj] = __builtin_amdgcn_mfma_f32_16x16x32_bf16(fah, fbh[nj], acc[mi][nj], 0, 0, 0);
                acc[mi][nj] = __builtin_amdgcn_mfma_f32_16x16x32_bf16(fah, fbl[nj], acc[mi][nj], 0, 0, 0);
                acc[mi][nj] = __builtin_amdgcn_mfma_f32_16x16x32_bf16(fal, fbh[nj], acc[mi][nj], 0, 0, 0);
            }
        }
        __syncthreads();
    }
    // C/D layout: col = lane&15, row = (lane>>4)*4 + reg  [m89-verified]
    #pragma unroll
    for (int nj = 0; nj < 4; ++nj) {
        int col = bn + wc + nj * 16 + l16;
        float bb = bias ? bias[col] : 0.f;
        #pragma unroll
        for (int mi = 0; mi < 4; ++mi) {
            int row0 = bm + wr + mi * 16 + (lane >> 4) * 4;
            #pragma unroll
            for (int r = 0; r < 4; ++r)
                C[(size_t)(row0 + r) * N + col] = acc[mi][nj][r] + bb;
        }
    }
}

// ---------------------------------------------------------------------------
// out[M,D] = part0 + part1 + bias   (split-K combine for gemm2)
// ---------------------------------------------------------------------------
__global__ __launch_bounds__(256)
void combine2(const float* __restrict__ part, const float* __restrict__ ob,
              float* __restrict__ out)
{
    int i = blockIdx.x * 256 + threadIdx.x;        // MM*D_/4
    float4 a = ((const float4*)part)[i];
    float4 b = ((const float4*)(part + (size_t)MM * D_))[i];
    float4 bb = *(const float4*)(ob + ((i & (D_/4 - 1)) << 2));
    float4 o;
    o.x = a.x + b.x + bb.x; o.y = a.y + b.y + bb.y;
    o.z = a.z + b.z + bb.z; o.w = a.w + b.w + bb.w;
    ((float4*)out)[i] = o;
}

// ---------------------------------------------------------------------------
// u = silu(depthwise_conv3(h) + conv_b)
// ---------------------------------------------------------------------------
__global__ __launch_bounds__(256)
void conv_silu(const float* __restrict__ h, const float* __restrict__ cw,
               const float* __restrict__ cb, float* __restrict__ u)
{
    size_t idx = (size_t)blockIdx.x * 256 + threadIdx.x;   // B*L*DI
    int    di  = idx & (DI_ - 1);
    size_t bl  = idx >> 11;
    int    l   = (int)(bl & (L_ - 1));
    float s = cb[di] + h[idx] * cw[di * 3 + 1];
    if (l > 0)      s += h[idx - DI_] * cw[di * 3 + 0];
    if (l < L_ - 1) s += h[idx + DI_] * cw[di * 3 + 2];
    u[idx] = s / (1.f + __expf(-s));
}

// ---------------------------------------------------------------------------
// xproj stage A: partial[s][m][c] = sum_{k in slice s} u[m][k]*xw[c][k]
// ---------------------------------------------------------------------------
__global__ __launch_bounds__(256)
void xprojA(const float* __restrict__ u, const float* __restrict__ xw,
            float* __restrict__ part)
{
    __shared__ float ut[32][132];
    __shared__ float wt[80][132];
    const int t  = threadIdx.x;
    const int bm = blockIdx.x * 32;
    const int ks = blockIdx.y;
    const int r2 = t & 15, cg = t >> 4;
    float acc[2][5] = {};
    for (int ch = 0; ch < 2; ++ch) {
        const int kb = ks * 256 + ch * 128;
        {
            int sr = t >> 3, k4 = (t & 7) * 4;
            #pragma unroll
            for (int i = 0; i < 4; ++i) {
                float4 v = *(const float4*)(u + (size_t)(bm + sr) * DI_ + kb + k4 + 32 * i);
                ut[sr][k4 + 32*i + 0] = v.x; ut[sr][k4 + 32*i + 1] = v.y;
                ut[sr][k4 + 32*i + 2] = v.z; ut[sr][k4 + 32*i + 3] = v.w;
            }
        }
        #pragma unroll
        for (int i = 0; i < 10; ++i) {
            int idx = t + 256 * i;
            int wrow = idx >> 5, k4 = (idx & 31) * 4;
            float4 v = *(const float4*)(xw + (size_t)wrow * DI_ + kb + k4);
            wt[wrow][k4 + 0] = v.x; wt[wrow][k4 + 1] = v.y;
            wt[wrow][k4 + 2] = v.z; wt[wrow][k4 + 3] = v.w;
        }
        __syncthreads();
        for (int k = 0; k < 128; k += 4) {
            float4 u0 = *(const float4*)&ut[r2][k];
            float4 u1 = *(const float4*)&ut[r2 + 16][k];
            #pragma unroll
            for (int c = 0; c < 5; ++c) {
                float4 wv = *(const float4*)&wt[cg * 5 + c][k];
                acc[0][c] = fmaf(u0.x, wv.x, fmaf(u0.y, wv.y, fmaf(u0.z, wv.z, fmaf(u0.w, wv.w, acc[0][c]))));
                acc[1][c] = fmaf(u1.x, wv.x, fmaf(u1.y, wv.y, fmaf(u1.z, wv.z, fmaf(u1.w, wv.w, acc[1][c]))));
            }
        }
        __syncthreads();
    }
    size_t b0 = ((size_t)ks * MM + bm + r2) * 80 + cg * 5;
    size_t b1 = ((size_t)ks * MM + bm + r2 + 16) * 80 + cg * 5;
    #pragma unroll
    for (int c = 0; c < 5; ++c) { part[b0 + c] = acc[0][c]; part[b1 + c] = acc[1][c]; }
}

__global__ __launch_bounds__(256)
void xprojB(const float* __restrict__ part, const float* __restrict__ xpb,
            float* __restrict__ xdbl)
{
    int idx = blockIdx.x * 256 + threadIdx.x;   // MM*80
    int c = idx % 80;
    float s = xpb[c];
    #pragma unroll
    for (int sl = 0; sl < XKS; ++sl)
        s += part[(size_t)sl * (MM * 80) + idx];
    xdbl[idx] = s;
}

__global__ __launch_bounds__(256)
void transpose_dtw(const float* __restrict__ dtw, float* __restrict__ dtwT)
{
    int idx = blockIdx.x * 256 + threadIdx.x;   // RR*DI
    int di  = idx & (DI_ - 1);
    int r   = idx >> 11;
    dtwT[(size_t)r * DI_ + di] = dtw[(size_t)di * RR + r];
}

// ---------------------------------------------------------------------------
// delta[M,DI] = softplus(xdbl[:, :64] @ dtwT + dt_b)
// ---------------------------------------------------------------------------
__global__ __launch_bounds__(256)
void delta_gemm(const float* __restrict__ xdbl, const float* __restrict__ dtwT,
                const float* __restrict__ dtb, float* __restrict__ delta)
{
    __shared__ float dl[16][64];
    const int t    = threadIdx.x;
    const int row0 = blockIdx.y * 16;
    const int col  = blockIdx.x * 256 + t;
    {
        int sr = t >> 4, sk = (t & 15) << 2;
        float4 v = *(const float4*)(xdbl + (size_t)(row0 + sr) * 80 + sk);
        dl[sr][sk] = v.x; dl[sr][sk+1] = v.y; dl[sr][sk+2] = v.z; dl[sr][sk+3] = v.w;
    }
    __syncthreads();
    float acc[16] = {};
    for (int k = 0; k < 64; ++k) {
        float w = dtwT[(size_t)k * DI_ + col];
        #pragma unroll
        for (int rr = 0; rr < 16; ++rr)
            acc[rr] = fmaf(dl[rr][k], w, acc[rr]);
    }
    float bias = dtb[col];
    #pragma unroll
    for (int rr = 0; rr < 16; ++rr) {
        float x  = acc[rr] + bias;
        float sp = fmaxf(x, 0.f) + log1pf(__expf(-fabsf(x)));
        delta[(size_t)(row0 + rr) * DI_ + col] = sp;
    }
}

// ---------------------------------------------------------------------------
// Scan pass A: per (b, chunk, di) compute P[n]=prod(dA), S[n]=scan-from-zero
// ---------------------------------------------------------------------------
__global__ __launch_bounds__(256)
void scanA(const float* __restrict__ delta, const float* __restrict__ u,
           const float* __restrict__ xdbl, const float* __restrict__ A_log,
           float* __restrict__ Pbuf, float* __restrict__ Sbuf)
{
    const int tid  = blockIdx.x * 256 + threadIdx.x;   // B*NC*DI
    const int di   = tid & (DI_ - 1);
    const int rest = tid >> 11;
    const int ch   = rest & (NC - 1);
    const int b    = rest >> 5;
    float A2[NS];
    {
        const float4* ap = (const float4*)(A_log + (size_t)di * NS);
        #pragma unroll
        for (int q = 0; q < 4; ++q) {
            float4 v = ap[q];
            A2[q*4+0] = -__expf(v.x) * 1.44269504f;
            A2[q*4+1] = -__expf(v.y) * 1.44269504f;
            A2[q*4+2] = -__expf(v.z) * 1.44269504f;
            A2[q*4+3] = -__expf(v.w) * 1.44269504f;
        }
    }
    float c[NS], P[NS];
    #pragma unroll
    for (int n = 0; n < NS; ++n) { c[n] = 0.f; P[n] = 1.f; }
    const size_t l0 = (size_t)b * L_ + (size_t)ch * CL;
    const float* dp = delta + l0 * DI_ + di;
    const float* up = u     + l0 * DI_ + di;
    const float* xp = xdbl  + l0 * 80 + RR;
    for (int l = 0; l < CL; ++l) {
        float dlt = dp[(size_t)l * DI_];
        float du  = dlt * up[(size_t)l * DI_];
        const float4* bp = (const float4*)(xp + (size_t)l * 80);
        #pragma unroll
        for (int q = 0; q < 4; ++q) {
            float4 bv = bp[q];
            float bn_[4] = {bv.x, bv.y, bv.z, bv.w};
            #pragma unroll
            for (int j = 0; j < 4; ++j) {
                int   n = q * 4 + j;
                float a = exp2f(dlt * A2[n]);
                c[n] = fmaf(a, c[n], du * bn_[j]);
                P[n] *= a;
            }
        }
    }
    float4* Pp = (float4*)(Pbuf + (size_t)tid * NS);
    float4* Sp = (float4*)(Sbuf + (size_t)tid * NS);
    #pragma unroll
    for (int q = 0; q < 4; ++q) {
        Pp[q] = make_float4(P[q*4], P[q*4+1], P[q*4+2], P[q*4+3]);
        Sp[q] = make_float4(c[q*4], c[q*4+1], c[q*4+2], c[q*4+3]);
    }
}

__global__ __launch_bounds__(256)
void scanB(const float* __restrict__ Pbuf, const float* __restrict__ Sbuf,
           float* __restrict__ start)
{
    const int tid = blockIdx.x * 256 + threadIdx.x;   // B*DI*NS
    const int n   = tid & (NS - 1);
    const int di  = (tid >> 4) & (DI_ - 1);
    const int b   = tid >> 15;
    float c = 0.f;
    for (int ch = 0; ch < NC; ++ch) {
        size_t idx = ((size_t)(b * NC + ch) * DI_ + di) * NS + n;
        start[idx] = c;
        c = fmaf(Pbuf[idx], c, Sbuf[idx]);
    }
}

// ---------------------------------------------------------------------------
// Scan pass C: replay from start state; y emitted directly as bf16 hi/lo
// ---------------------------------------------------------------------------
__global__ __launch_bounds__(256)
void scanC(const float* __restrict__ delta, const float* __restrict__ u,
           const float* __restrict__ xdbl, const float* __restrict__ A_log,
           const float* __restrict__ Dp, const float* __restrict__ start,
           ushort* __restrict__ yh, ushort* __restrict__ yl)
{
    const int tid  = blockIdx.x * 256 + threadIdx.x;
    const int di   = tid & (DI_ - 1);
    const int rest = tid >> 11;
    const int ch   = rest & (NC - 1);
    const int b    = rest >> 5;
    float A2[NS];
    {
        const float4* ap = (const float4*)(A_log + (size_t)di * NS);
        #pragma unroll
        for (int q = 0; q < 4; ++q) {
            float4 v = ap[q];
            A2[q*4+0] = -__expf(v.x) * 1.44269504f;
            A2[q*4+1] = -__expf(v.y) * 1.44269504f;
            A2[q*4+2] = -__expf(v.z) * 1.44269504f;
            A2[q*4+3] = -__expf(v.w) * 1.44269504f;
        }
    }
    float c[NS];
    {
        const float4* sp = (const float4*)(start + (size_t)tid * NS);
        #pragma unroll
        for (int q = 0; q < 4; ++q) {
            float4 v = sp[q];
            c[q*4+0] = v.x; c[q*4+1] = v.y; c[q*4+2] = v.z; c[q*4+3] = v.w;
        }
    }
    const float Dpar = Dp[di];
    const size_t l0 = (size_t)b * L_ + (size_t)ch * CL;
    const float* dp = delta + l0 * DI_ + di;
    const float* up = u     + l0 * DI_ + di;
    const float* xp = xdbl  + l0 * 80 + RR;
    for (int l = 0; l < CL; ++l) {
        float dlt = dp[(size_t)l * DI_];
        float uu  = up[(size_t)l * DI_];
        float du  = dlt * uu;
        const float4* bp = (const float4*)(xp + (size_t)l * 80);
        float sum = 0.f;
        #pragma unroll
        for (int q = 0; q < 4; ++q) {
            float4 bv = bp[q];
            float bn_[4] = {bv.x, bv.y, bv.z, bv.w};
            #pragma unroll
            for (int j = 0; j < 4; ++j) {
                int   n = q * 4 + j;
                float a = exp2f(dlt * A2[n]);
                c[n] = fmaf(a, c[n], du * bn_[j]);
                sum += c[n];
            }
        }
        float y = sum + uu * Dpar;
        ushort hb = f2bf_rn(y);
        size_t oi = (l0 + l) * DI_ + di;
        yh[oi] = hb;
        yl[oi] = f2bf_rn(y - bf2f(hb));
    }
}

// ---------------------------------------------------------------------------
extern "C" void kernel_launch(void* const* d_in, const int* in_sizes, int n_in,
                              void* d_out, int out_size, void* d_ws, size_t ws_size,
                              hipStream_t stream)
{
    const float* x      = (const float*)d_in[0];
    const float* in_w   = (const float*)d_in[1];
    const float* in_b   = (const float*)d_in[2];
    const float* conv_w = (const float*)d_in[3];
    const float* conv_b = (const float*)d_in[4];
    const float* xpw    = (const float*)d_in[5];
    const float* xpb    = (const float*)d_in[6];
    const float* dt_w   = (const float*)d_in[7];
    const float* dt_b   = (const float*)d_in[8];
    const float* A_log  = (const float*)d_in[9];
    const float* Dpar   = (const float*)d_in[10];
    const float* out_w  = (const float*)d_in[11];
    const float* out_b  = (const float*)d_in[12];
    float*       out    = (float*)d_out;

    char* ws  = (char*)d_ws;
    size_t off = 0;
    auto alloc = [&](size_t bytes) {
        void* p = ws + off; off = (off + bytes + 255) & ~(size_t)255; return p;
    };
    const size_t pse = (size_t)B_ * NC * DI_ * NS;   // scan summary elems (2M)
    float*  u_    = (float*)alloc((size_t)MM * DI_ * 4);   // u; later gemm2 partials
    float*  h_    = (float*)alloc((size_t)MM * DI_ * 4);   // h -> delta
    float*  xdbl  = (float*)alloc((size_t)MM * 80 * 4);
    float*  dtwT  = (float*)alloc((size_t)RR * DI_ * 4);
    ushort* yh    = (ushort*)alloc((size_t)MM * DI_ * 2);  // aliases: xpart, Pbuf
    ushort* yl    = (ushort*)alloc((size_t)MM * DI_ * 2);  // aliases: Sbuf
    float*  stbuf = (float*)alloc(pse * 4);
    ushort* xh    = (ushort*)alloc((size_t)MM * D_ * 2);
    ushort* xl    = (ushort*)alloc((size_t)MM * D_ * 2);
    ushort* wih   = (ushort*)alloc((size_t)DI_ * D_ * 2);
    ushort* wil   = (ushort*)alloc((size_t)DI_ * D_ * 2);
    ushort* woh   = (ushort*)alloc((size_t)D_ * DI_ * 2);
    ushort* wol   = (ushort*)alloc((size_t)D_ * DI_ * 2);
    float*  xpart = (float*)yh;     // 10.5 MB <= 16.8 MB region
    float*  Pbuf  = (float*)yh;     // 8.4 MB
    float*  Sbuf  = (float*)yl;
    float*  part2 = u_;             // gemm2 split-K partials (2x16.8 = 33.6 MB)

    // 0. bf16 hi/lo conversions
    cvt_hilo<<<(MM * D_ / 4 + 255) / 256, 256, 0, stream>>>(x, xh, xl, MM * D_ / 4);
    cvt_hilo<<<(DI_ * D_ / 4 + 255) / 256, 256, 0, stream>>>(in_w, wih, wil, DI_ * D_ / 4);
    cvt_hilo<<<(D_ * DI_ / 4 + 255) / 256, 256, 0, stream>>>(out_w, woh, wol, D_ * DI_ / 4);
    // 1. h = x @ in_w^T + in_b   [4096 x 2048], K=1024
    gemm_bf16x3<<<dim3(DI_ / 128, MM / 128, 1), 256, 0, stream>>>(
        xh, xl, wih, wil, in_b, h_, D_, DI_, D_);
    // 2. u = silu(conv3(h) + conv_b)
    conv_silu<<<(MM * DI_) / 256, 256, 0, stream>>>(h_, conv_w, conv_b, u_);
    // 3. x_dbl = u @ x_proj_w^T + x_proj_b  (split-K two-stage)
    xprojA<<<dim3(MM / 32, XKS), 256, 0, stream>>>(u_, xpw, xpart);
    xprojB<<<(MM * 80) / 256, 256, 0, stream>>>(xpart, xpb, xdbl);
    // 4. dt_w transpose
    transpose_dtw<<<(RR * DI_) / 256, 256, 0, stream>>>(dt_w, dtwT);
    // 5. delta = softplus(delta_lr @ dt_w^T + dt_b)  -> h_
    delta_gemm<<<dim3(DI_ / 256, MM / 16), 256, 0, stream>>>(xdbl, dtwT, dt_b, h_);
    // 6-8. chunked selective scan; y emitted as bf16 hi/lo
    scanA<<<(B_ * NC * DI_) / 256, 256, 0, stream>>>(h_, u_, xdbl, A_log, Pbuf, Sbuf);
    scanB<<<(B_ * DI_ * NS) / 256, 256, 0, stream>>>(Pbuf, Sbuf, stbuf);
    scanC<<<(B_ * NC * DI_) / 256, 256, 0, stream>>>(h_, u_, xdbl, A_log, Dpar, stbuf, yh, yl);
    // 9. out = y @ out_w^T + out_b  [4096 x 1024], K=2048, split-K=2
    gemm_bf16x3<<<dim3(D_ / 128, MM / 128, 2), 256, 0, stream>>>(
        yh, yl, woh, wol, nullptr, part2, DI_, D_, DI_ / 2);
    combine2<<<(MM * D_ / 4) / 256, 256, 0, stream>>>(part2, out_b, out);
}

// Round 8
// 434.440 us; speedup vs baseline: 2.4237x; 1.0458x over previous
//
#include <hip/hip_runtime.h>

#define B_  2
#define L_  2048
#define D_  1024
#define DI_ 2048
#define NS  16
#define RR  64
#define MM  (B_*L_)      // 4096 rows
#define NC  64           // scan chunks (32 -> 64 for occupancy)
#define CL  (L_/NC)      // 32 steps per chunk
#define XKS 8            // xproj split-K slices

typedef __attribute__((ext_vector_type(8))) short bf16x8;
typedef __attribute__((ext_vector_type(4))) float f32x4;

__device__ __forceinline__ ushort f2bf_rn(float f) {
    union { float f; unsigned u; } v; v.f = f;
    unsigned r = v.u + 0x7FFF + ((v.u >> 16) & 1);
    return (ushort)(r >> 16);
}
__device__ __forceinline__ float bf2f(ushort h) {
    union { unsigned u; float f; } v; v.u = ((unsigned)h) << 16;
    return v.f;
}
__device__ __forceinline__ void gload_lds16(const ushort* g, ushort* l) {
    __builtin_amdgcn_global_load_lds(
        (const __attribute__((address_space(1))) void*)(g),
        (__attribute__((address_space(3))) void*)(l), 16, 0, 0);
}

// ---------------------------------------------------------------------------
// cvt: fp32 -> bf16 hi/lo pair (elementwise, n multiple of 4)
// ---------------------------------------------------------------------------
__global__ __launch_bounds__(256)
void cvt_hilo(const float* __restrict__ in, ushort* __restrict__ hi,
              ushort* __restrict__ lo, int n4)
{
    int i = blockIdx.x * 256 + threadIdx.x;
    if (i >= n4) return;
    float4 v = ((const float4*)in)[i];
    ushort4 h, l;
    h.x = f2bf_rn(v.x); l.x = f2bf_rn(v.x - bf2f(h.x));
    h.y = f2bf_rn(v.y); l.y = f2bf_rn(v.y - bf2f(h.y));
    h.z = f2bf_rn(v.z); l.z = f2bf_rn(v.z - bf2f(h.z));
    h.w = f2bf_rn(v.w); l.w = f2bf_rn(v.w - bf2f(h.w));
    ((ushort4*)hi)[i] = h; ((ushort4*)lo)[i] = l;
}

// ---------------------------------------------------------------------------
// C[M,N] = A@W^T (+bias) via bf16x3: hi*hi + hi*lo + lo*hi, fp32 accum.
// Tile 128x128, BK=32, 256 thr = 4 waves, each wave 64x64 (4x4 16x16 frags).
// Staging: global_load_lds w=16, linear LDS dest, swizzle via global source
// slot (i&3)^((i>>3)&3); reads use slot (lane>>4)^((l16>>1)&3)  [rule 21].
// gridDim.z = split-K; partial z writes C + z*MM*N.
// ---------------------------------------------------------------------------
__global__ __launch_bounds__(256, 2)
void gemm_bf16x3(const ushort* __restrict__ Ah, const ushort* __restrict__ Al,
                 const ushort* __restrict__ Bh, const ushort* __restrict__ Bl,
                 const float* __restrict__ bias, float* __restrict__ C,
                 int lda, int N, int kPerSplit)
{
    __shared__ ushort sAh[128*32], sAl[128*32], sBh[128*32], sBl[128*32];
    const int t    = threadIdx.x;
    const int bm   = blockIdx.y * 128, bn = blockIdx.x * 128;
    const int lane = t & 63, w = t >> 6;
    const int wr   = (w >> 1) * 64, wc = (w & 1) * 64;
    const int l16  = lane & 15;
    const int kbeg = blockIdx.z * kPerSplit;
    C += (size_t)blockIdx.z * MM * N;

    const int srow  = lane >> 2;
    const int sslot = (lane & 3) ^ ((lane >> 3) & 3);   // inverse-swizzled source
    const int r0 = 32 * w + srow, r1 = r0 + 16;
    const ushort* gAh0 = Ah + (size_t)(bm + r0) * lda + sslot * 8 + kbeg;
    const ushort* gAh1 = Ah + (size_t)(bm + r1) * lda + sslot * 8 + kbeg;
    const ushort* gAl0 = Al + (size_t)(bm + r0) * lda + sslot * 8 + kbeg;
    const ushort* gAl1 = Al + (size_t)(bm + r1) * lda + sslot * 8 + kbeg;
    const ushort* gBh0 = Bh + (size_t)(bn + r0) * lda + sslot * 8 + kbeg;
    const ushort* gBh1 = Bh + (size_t)(bn + r1) * lda + sslot * 8 + kbeg;
    const ushort* gBl0 = Bl + (size_t)(bn + r0) * lda + sslot * 8 + kbeg;
    const ushort* gBl1 = Bl + (size_t)(bn + r1) * lda + sslot * 8 + kbeg;
    ushort* lA0 = sAh + 1024 * w;
    ushort* lA1 = sAh + 1024 * w + 512;
    ushort* lAl0 = sAl + 1024 * w, *lAl1 = sAl + 1024 * w + 512;
    ushort* lB0 = sBh + 1024 * w, *lB1 = sBh + 1024 * w + 512;
    ushort* lBl0 = sBl + 1024 * w, *lBl1 = sBl + 1024 * w + 512;

    const int swz = ((lane >> 4) ^ ((l16 >> 1) & 3));   // 16B slot
    const int offA = (wr + l16) * 32 + swz * 8;         // + mi*512
    const int offB = (wc + l16) * 32 + swz * 8;         // + nj*512

    f32x4 acc[4][4];
    #pragma unroll
    for (int i = 0; i < 4; ++i)
        #pragma unroll
        for (int j = 0; j < 4; ++j)
            acc[i][j] = (f32x4){0.f, 0.f, 0.f, 0.f};

    for (int k0 = 0; k0 < kPerSplit; k0 += 32) {
        gload_lds16(gAh0 + k0, lA0);  gload_lds16(gAh1 + k0, lA1);
        gload_lds16(gAl0 + k0, lAl0); gload_lds16(gAl1 + k0, lAl1);
        gload_lds16(gBh0 + k0, lB0);  gload_lds16(gBh1 + k0, lB1);
        gload_lds16(gBl0 + k0, lBl0); gload_lds16(gBl1 + k0, lBl1);
        __syncthreads();
        bf16x8 fbh[4], fbl[4];
        #pragma unroll
        for (int nj = 0; nj < 4; ++nj) {
            fbh[nj] = *(const bf16x8*)(sBh + offB + nj * 512);
            fbl[nj] = *(const bf16x8*)(sBl + offB + nj * 512);
        }
        #pragma unroll
        for (int mi = 0; mi < 4; ++mi) {
            bf16x8 fah = *(const bf16x8*)(sAh + offA + mi * 512);
            bf16x8 fal = *(const bf16x8*)(sAl + offA + mi * 512);
            #pragma unroll
            for (int nj = 0; nj < 4; ++nj) {
                acc[mi][nj] = __builtin_amdgcn_mfma_f32_16x16x32_bf16(fah, fbh[nj], acc[mi][nj], 0, 0, 0);
                acc[mi][nj] = __builtin_amdgcn_mfma_f32_16x16x32_bf16(fah, fbl[nj], acc[mi][nj], 0, 0, 0);
                acc[mi][nj] = __builtin_amdgcn_mfma_f32_16x16x32_bf16(fal, fbh[nj], acc[mi][nj], 0, 0, 0);
            }
        }
        __syncthreads();
    }
    // C/D layout: col = lane&15, row = (lane>>4)*4 + reg  [m89-verified]
    #pragma unroll
    for (int nj = 0; nj < 4; ++nj) {
        int col = bn + wc + nj * 16 + l16;
        float bb = bias ? bias[col] : 0.f;
        #pragma unroll
        for (int mi = 0; mi < 4; ++mi) {
            int row0 = bm + wr + mi * 16 + (lane >> 4) * 4;
            #pragma unroll
            for (int r = 0; r < 4; ++r)
                C[(size_t)(row0 + r) * N + col] = acc[mi][nj][r] + bb;
        }
    }
}

// ---------------------------------------------------------------------------
// out[M,D] = part0 + part1 + bias   (split-K combine for gemm2)
// ---------------------------------------------------------------------------
__global__ __launch_bounds__(256)
void combine2(const float* __restrict__ part, const float* __restrict__ ob,
              float* __restrict__ out)
{
    int i = blockIdx.x * 256 + threadIdx.x;        // MM*D_/4
    float4 a = ((const float4*)part)[i];
    float4 b = ((const float4*)(part + (size_t)MM * D_))[i];
    float4 bb = *(const float4*)(ob + ((i & (D_/4 - 1)) << 2));
    float4 o;
    o.x = a.x + b.x + bb.x; o.y = a.y + b.y + bb.y;
    o.z = a.z + b.z + bb.z; o.w = a.w + b.w + bb.w;
    ((float4*)out)[i] = o;
}

// ---------------------------------------------------------------------------
// u = silu(depthwise_conv3(h) + conv_b)  — float4-vectorized along di
// ---------------------------------------------------------------------------
__global__ __launch_bounds__(256)
void conv_silu(const float* __restrict__ h, const float* __restrict__ cw,
               const float* __restrict__ cb, float* __restrict__ u)
{
    size_t i4 = ((size_t)blockIdx.x * 256 + threadIdx.x) << 2;   // elem index
    int    di = (int)(i4 & (DI_ - 1));
    int    l  = (int)((i4 >> 11) & (L_ - 1));
    float4 cc = *(const float4*)(h + i4);
    float4 lf = make_float4(0.f, 0.f, 0.f, 0.f);
    float4 rt = make_float4(0.f, 0.f, 0.f, 0.f);
    if (l > 0)      lf = *(const float4*)(h + i4 - DI_);
    if (l < L_ - 1) rt = *(const float4*)(h + i4 + DI_);
    float4 bb = *(const float4*)(cb + di);
    float cin[4]  = {cc.x, cc.y, cc.z, cc.w};
    float lin[4]  = {lf.x, lf.y, lf.z, lf.w};
    float rin[4]  = {rt.x, rt.y, rt.z, rt.w};
    float bin[4]  = {bb.x, bb.y, bb.z, bb.w};
    float res[4];
    #pragma unroll
    for (int j = 0; j < 4; ++j) {
        const float* w = cw + (size_t)(di + j) * 3;
        float s = bin[j] + lin[j] * w[0] + cin[j] * w[1] + rin[j] * w[2];
        res[j] = s / (1.f + __expf(-s));
    }
    *(float4*)(u + i4) = make_float4(res[0], res[1], res[2], res[3]);
}

// ---------------------------------------------------------------------------
// xproj stage A: partial[s][m][c] = sum_{k in slice s} u[m][k]*xw[c][k]
// ---------------------------------------------------------------------------
__global__ __launch_bounds__(256)
void xprojA(const float* __restrict__ u, const float* __restrict__ xw,
            float* __restrict__ part)
{
    __shared__ float ut[32][132];
    __shared__ float wt[80][132];
    const int t  = threadIdx.x;
    const int bm = blockIdx.x * 32;
    const int ks = blockIdx.y;
    const int r2 = t & 15, cg = t >> 4;
    float acc[2][5] = {};
    for (int ch = 0; ch < 2; ++ch) {
        const int kb = ks * 256 + ch * 128;
        {
            int sr = t >> 3, k4 = (t & 7) * 4;
            #pragma unroll
            for (int i = 0; i < 4; ++i) {
                float4 v = *(const float4*)(u + (size_t)(bm + sr) * DI_ + kb + k4 + 32 * i);
                ut[sr][k4 + 32*i + 0] = v.x; ut[sr][k4 + 32*i + 1] = v.y;
                ut[sr][k4 + 32*i + 2] = v.z; ut[sr][k4 + 32*i + 3] = v.w;
            }
        }
        #pragma unroll
        for (int i = 0; i < 10; ++i) {
            int idx = t + 256 * i;
            int wrow = idx >> 5, k4 = (idx & 31) * 4;
            float4 v = *(const float4*)(xw + (size_t)wrow * DI_ + kb + k4);
            wt[wrow][k4 + 0] = v.x; wt[wrow][k4 + 1] = v.y;
            wt[wrow][k4 + 2] = v.z; wt[wrow][k4 + 3] = v.w;
        }
        __syncthreads();
        for (int k = 0; k < 128; k += 4) {
            float4 u0 = *(const float4*)&ut[r2][k];
            float4 u1 = *(const float4*)&ut[r2 + 16][k];
            #pragma unroll
            for (int c = 0; c < 5; ++c) {
                float4 wv = *(const float4*)&wt[cg * 5 + c][k];
                acc[0][c] = fmaf(u0.x, wv.x, fmaf(u0.y, wv.y, fmaf(u0.z, wv.z, fmaf(u0.w, wv.w, acc[0][c]))));
                acc[1][c] = fmaf(u1.x, wv.x, fmaf(u1.y, wv.y, fmaf(u1.z, wv.z, fmaf(u1.w, wv.w, acc[1][c]))));
            }
        }
        __syncthreads();
    }
    size_t b0 = ((size_t)ks * MM + bm + r2) * 80 + cg * 5;
    size_t b1 = ((size_t)ks * MM + bm + r2 + 16) * 80 + cg * 5;
    #pragma unroll
    for (int c = 0; c < 5; ++c) { part[b0 + c] = acc[0][c]; part[b1 + c] = acc[1][c]; }
}

__global__ __launch_bounds__(256)
void xprojB(const float* __restrict__ part, const float* __restrict__ xpb,
            float* __restrict__ xdbl)
{
    int idx = blockIdx.x * 256 + threadIdx.x;   // MM*80
    int c = idx % 80;
    float s = xpb[c];
    #pragma unroll
    for (int sl = 0; sl < XKS; ++sl)
        s += part[(size_t)sl * (MM * 80) + idx];
    xdbl[idx] = s;
}

__global__ __launch_bounds__(256)
void transpose_dtw(const float* __restrict__ dtw, float* __restrict__ dtwT)
{
    int idx = blockIdx.x * 256 + threadIdx.x;   // RR*DI
    int di  = idx & (DI_ - 1);
    int r   = idx >> 11;
    dtwT[(size_t)r * DI_ + di] = dtw[(size_t)di * RR + r];
}

// ---------------------------------------------------------------------------
// delta[M,DI] = softplus(xdbl[:, :64] @ dtwT + dt_b)
// ---------------------------------------------------------------------------
__global__ __launch_bounds__(256)
void delta_gemm(const float* __restrict__ xdbl, const float* __restrict__ dtwT,
                const float* __restrict__ dtb, float* __restrict__ delta)
{
    __shared__ float dl[16][64];
    const int t    = threadIdx.x;
    const int row0 = blockIdx.y * 16;
    const int col  = blockIdx.x * 256 + t;
    {
        int sr = t >> 4, sk = (t & 15) << 2;
        float4 v = *(const float4*)(xdbl + (size_t)(row0 + sr) * 80 + sk);
        dl[sr][sk] = v.x; dl[sr][sk+1] = v.y; dl[sr][sk+2] = v.z; dl[sr][sk+3] = v.w;
    }
    __syncthreads();
    float acc[16] = {};
    for (int k = 0; k < 64; ++k) {
        float w = dtwT[(size_t)k * DI_ + col];
        #pragma unroll
        for (int rr = 0; rr < 16; ++rr)
            acc[rr] = fmaf(dl[rr][k], w, acc[rr]);
    }
    float bias = dtb[col];
    #pragma unroll
    for (int rr = 0; rr < 16; ++rr) {
        float x  = acc[rr] + bias;
        float sp = fmaxf(x, 0.f) + log1pf(__expf(-fabsf(x)));
        delta[(size_t)(row0 + rr) * DI_ + col] = sp;
    }
}

// ---------------------------------------------------------------------------
// Scan pass A: per (b, chunk, di) compute P[n]=prod(dA), S[n]=scan-from-zero
// ---------------------------------------------------------------------------
__global__ __launch_bounds__(256)
void scanA(const float* __restrict__ delta, const float* __restrict__ u,
           const float* __restrict__ xdbl, const float* __restrict__ A_log,
           float* __restrict__ Pbuf, float* __restrict__ Sbuf)
{
    const int tid  = blockIdx.x * 256 + threadIdx.x;   // B*NC*DI
    const int di   = tid & (DI_ - 1);
    const int rest = tid >> 11;
    const int ch   = rest & (NC - 1);
    const int b    = rest >> 6;
    float A2[NS];
    {
        const float4* ap = (const float4*)(A_log + (size_t)di * NS);
        #pragma unroll
        for (int q = 0; q < 4; ++q) {
            float4 v = ap[q];
            A2[q*4+0] = -__expf(v.x) * 1.44269504f;
            A2[q*4+1] = -__expf(v.y) * 1.44269504f;
            A2[q*4+2] = -__expf(v.z) * 1.44269504f;
            A2[q*4+3] = -__expf(v.w) * 1.44269504f;
        }
    }
    float c[NS], P[NS];
    #pragma unroll
    for (int n = 0; n < NS; ++n) { c[n] = 0.f; P[n] = 1.f; }
    const size_t l0 = (size_t)b * L_ + (size_t)ch * CL;
    const float* dp = delta + l0 * DI_ + di;
    const float* up = u     + l0 * DI_ + di;
    const float* xp = xdbl  + l0 * 80 + RR;
    for (int l = 0; l < CL; ++l) {
        float dlt = dp[(size_t)l * DI_];
        float du  = dlt * up[(size_t)l * DI_];
        const float4* bp = (const float4*)(xp + (size_t)l * 80);
        #pragma unroll
        for (int q = 0; q < 4; ++q) {
            float4 bv = bp[q];
            float bn_[4] = {bv.x, bv.y, bv.z, bv.w};
            #pragma unroll
            for (int j = 0; j < 4; ++j) {
                int   n = q * 4 + j;
                float a = exp2f(dlt * A2[n]);
                c[n] = fmaf(a, c[n], du * bn_[j]);
                P[n] *= a;
            }
        }
    }
    float4* Pp = (float4*)(Pbuf + (size_t)tid * NS);
    float4* Sp = (float4*)(Sbuf + (size_t)tid * NS);
    #pragma unroll
    for (int q = 0; q < 4; ++q) {
        Pp[q] = make_float4(P[q*4], P[q*4+1], P[q*4+2], P[q*4+3]);
        Sp[q] = make_float4(c[q*4], c[q*4+1], c[q*4+2], c[q*4+3]);
    }
}

__global__ __launch_bounds__(256)
void scanB(const float* __restrict__ Pbuf, const float* __restrict__ Sbuf,
           float* __restrict__ start)
{
    const int tid = blockIdx.x * 256 + threadIdx.x;   // B*DI*NS
    const int n   = tid & (NS - 1);
    const int di  = (tid >> 4) & (DI_ - 1);
    const int b   = tid >> 15;
    float c = 0.f;
    for (int ch = 0; ch < NC; ++ch) {
        size_t idx = ((size_t)(b * NC + ch) * DI_ + di) * NS + n;
        start[idx] = c;
        c = fmaf(Pbuf[idx], c, Sbuf[idx]);
    }
}

// ---------------------------------------------------------------------------
// Scan pass C: replay from start state; y emitted directly as bf16 hi/lo
// ---------------------------------------------------------------------------
__global__ __launch_bounds__(256)
void scanC(const float* __restrict__ delta, const float* __restrict__ u,
           const float* __restrict__ xdbl, const float* __restrict__ A_log,
           const float* __restrict__ Dp, const float* __restrict__ start,
           ushort* __restrict__ yh, ushort* __restrict__ yl)
{
    const int tid  = blockIdx.x * 256 + threadIdx.x;
    const int di   = tid & (DI_ - 1);
    const int rest = tid >> 11;
    const int ch   = rest & (NC - 1);
    const int b    = rest >> 6;
    float A2[NS];
    {
        const float4* ap = (const float4*)(A_log + (size_t)di * NS);
        #pragma unroll
        for (int q = 0; q < 4; ++q) {
            float4 v = ap[q];
            A2[q*4+0] = -__expf(v.x) * 1.44269504f;
            A2[q*4+1] = -__expf(v.y) * 1.44269504f;
            A2[q*4+2] = -__expf(v.z) * 1.44269504f;
            A2[q*4+3] = -__expf(v.w) * 1.44269504f;
        }
    }
    float c[NS];
    {
        const float4* sp = (const float4*)(start + (size_t)tid * NS);
        #pragma unroll
        for (int q = 0; q < 4; ++q) {
            float4 v = sp[q];
            c[q*4+0] = v.x; c[q*4+1] = v.y; c[q*4+2] = v.z; c[q*4+3] = v.w;
        }
    }
    const float Dpar = Dp[di];
    const size_t l0 = (size_t)b * L_ + (size_t)ch * CL;
    const float* dp = delta + l0 * DI_ + di;
    const float* up = u     + l0 * DI_ + di;
    const float* xp = xdbl  + l0 * 80 + RR;
    for (int l = 0; l < CL; ++l) {
        float dlt = dp[(size_t)l * DI_];
        float uu  = up[(size_t)l * DI_];
        float du  = dlt * uu;
        const float4* bp = (const float4*)(xp + (size_t)l * 80);
        float sum = 0.f;
        #pragma unroll
        for (int q = 0; q < 4; ++q) {
            float4 bv = bp[q];
            float bn_[4] = {bv.x, bv.y, bv.z, bv.w};
            #pragma unroll
            for (int j = 0; j < 4; ++j) {
                int   n = q * 4 + j;
                float a = exp2f(dlt * A2[n]);
                c[n] = fmaf(a, c[n], du * bn_[j]);
                sum += c[n];
            }
        }
        float y = sum + uu * Dpar;
        ushort hb = f2bf_rn(y);
        size_t oi = (l0 + l) * DI_ + di;
        yh[oi] = hb;
        yl[oi] = f2bf_rn(y - bf2f(hb));
    }
}

// ---------------------------------------------------------------------------
extern "C" void kernel_launch(void* const* d_in, const int* in_sizes, int n_in,
                              void* d_out, int out_size, void* d_ws, size_t ws_size,
                              hipStream_t stream)
{
    const float* x      = (const float*)d_in[0];
    const float* in_w   = (const float*)d_in[1];
    const float* in_b   = (const float*)d_in[2];
    const float* conv_w = (const float*)d_in[3];
    const float* conv_b = (const float*)d_in[4];
    const float* xpw    = (const float*)d_in[5];
    const float* xpb    = (const float*)d_in[6];
    const float* dt_w   = (const float*)d_in[7];
    const float* dt_b   = (const float*)d_in[8];
    const float* A_log  = (const float*)d_in[9];
    const float* Dpar   = (const float*)d_in[10];
    const float* out_w  = (const float*)d_in[11];
    const float* out_b  = (const float*)d_in[12];
    float*       out    = (float*)d_out;

    char* ws  = (char*)d_ws;
    size_t off = 0;
    auto alloc = [&](size_t bytes) {
        void* p = ws + off; off = (off + bytes + 255) & ~(size_t)255; return p;
    };
    float*  u_    = (float*)alloc((size_t)MM * DI_ * 4);   // u; later gemm2 partials
    float*  h_    = (float*)alloc((size_t)MM * DI_ * 4);   // h -> delta
    float*  xdbl  = (float*)alloc((size_t)MM * 80 * 4);
    float*  dtwT  = (float*)alloc((size_t)RR * DI_ * 4);
    ushort* yh    = (ushort*)alloc((size_t)MM * DI_ * 2);  // aliases: xpart, Pbuf (16.8MB)
    ushort* yl    = (ushort*)alloc((size_t)MM * DI_ * 2);  // aliases: Sbuf (16.8MB)
    ushort* xh    = (ushort*)alloc((size_t)MM * D_ * 2);   // dead after gemm1
    ushort* xl    = (ushort*)alloc((size_t)MM * D_ * 2);   //   -> stbuf aliases xh+xl
    ushort* wih   = (ushort*)alloc((size_t)DI_ * D_ * 2);
    ushort* wil   = (ushort*)alloc((size_t)DI_ * D_ * 2);
    ushort* woh   = (ushort*)alloc((size_t)D_ * DI_ * 2);
    ushort* wol   = (ushort*)alloc((size_t)D_ * DI_ * 2);
    float*  xpart = (float*)yh;     // 10.5 MB <= 16.8 MB
    float*  Pbuf  = (float*)yh;     // NC=64: B*NC*DI*NS*4 = 16.8 MB (exact fit)
    float*  Sbuf  = (float*)yl;
    float*  stbuf = (float*)xh;     // 16.8 MB spans xh+xl (both dead after gemm1)
    float*  part2 = u_;             // gemm2 split-K partials (2x16.8 = 33.6 MB)

    // 0. bf16 hi/lo conversions
    cvt_hilo<<<(MM * D_ / 4 + 255) / 256, 256, 0, stream>>>(x, xh, xl, MM * D_ / 4);
    cvt_hilo<<<(DI_ * D_ / 4 + 255) / 256, 256, 0, stream>>>(in_w, wih, wil, DI_ * D_ / 4);
    cvt_hilo<<<(D_ * DI_ / 4 + 255) / 256, 256, 0, stream>>>(out_w, woh, wol, D_ * DI_ / 4);
    // 1. h = x @ in_w^T + in_b   [4096 x 2048], K=1024
    gemm_bf16x3<<<dim3(DI_ / 128, MM / 128, 1), 256, 0, stream>>>(
        xh, xl, wih, wil, in_b, h_, D_, DI_, D_);
    // 2. u = silu(conv3(h) + conv_b)
    conv_silu<<<(MM * DI_ / 4) / 256, 256, 0, stream>>>(h_, conv_w, conv_b, u_);
    // 3. x_dbl = u @ x_proj_w^T + x_proj_b  (split-K two-stage)
    xprojA<<<dim3(MM / 32, XKS), 256, 0, stream>>>(u_, xpw, xpart);
    xprojB<<<(MM * 80) / 256, 256, 0, stream>>>(xpart, xpb, xdbl);
    // 4. dt_w transpose
    transpose_dtw<<<(RR * DI_) / 256, 256, 0, stream>>>(dt_w, dtwT);
    // 5. delta = softplus(delta_lr @ dt_w^T + dt_b)  -> h_
    delta_gemm<<<dim3(DI_ / 256, MM / 16), 256, 0, stream>>>(xdbl, dtwT, dt_b, h_);
    // 6-8. chunked selective scan (NC=64); y emitted as bf16 hi/lo
    scanA<<<(B_ * NC * DI_) / 256, 256, 0, stream>>>(h_, u_, xdbl, A_log, Pbuf, Sbuf);
    scanB<<<(B_ * DI_ * NS) / 256, 256, 0, stream>>>(Pbuf, Sbuf, stbuf);
    scanC<<<(B_ * NC * DI_) / 256, 256, 0, stream>>>(h_, u_, xdbl, A_log, Dpar, stbuf, yh, yl);
    // 9. out = y @ out_w^T + out_b  [4096 x 1024], K=2048, split-K=2
    gemm_bf16x3<<<dim3(D_ / 128, MM / 128, 2), 256, 0, stream>>>(
        yh, yl, woh, wol, nullptr, part2, DI_, D_, DI_ / 2);
    combine2<<<(MM * D_ / 4) / 256, 256, 0, stream>>>(part2, out_b, out);
}

// Round 9
// 418.040 us; speedup vs baseline: 2.5188x; 1.0392x over previous
//
#include <hip/hip_runtime.h>

#define B_  2
#define L_  2048
#define D_  1024
#define DI_ 2048
#define NS  16
#define RR  64
#define MM  (B_*L_)      // 4096 rows
#define NC  64           // scan chunks
#define CL  (L_/NC)      // 32 steps per chunk
#define XKS 8            // xproj split-K slices

typedef __attribute__((ext_vector_type(8))) short bf16x8;
typedef __attribute__((ext_vector_type(4))) float f32x4;

__device__ __forceinline__ ushort f2bf_rn(float f) {
    union { float f; unsigned u; } v; v.f = f;
    unsigned r = v.u + 0x7FFF + ((v.u >> 16) & 1);
    return (ushort)(r >> 16);
}
__device__ __forceinline__ float bf2f(ushort h) {
    union { unsigned u; float f; } v; v.u = ((unsigned)h) << 16;
    return v.f;
}
__device__ __forceinline__ void gload_lds16(const ushort* g, ushort* l) {
    __builtin_amdgcn_global_load_lds(
        (const __attribute__((address_space(1))) void*)(g),
        (__attribute__((address_space(3))) void*)(l), 16, 0, 0);
}

// ---------------------------------------------------------------------------
// cvt: fp32 -> bf16 hi/lo pair (elementwise, n multiple of 4)
// ---------------------------------------------------------------------------
__global__ __launch_bounds__(256)
void cvt_hilo(const float* __restrict__ in, ushort* __restrict__ hi,
              ushort* __restrict__ lo, int n4)
{
    int i = blockIdx.x * 256 + threadIdx.x;
    if (i >= n4) return;
    float4 v = ((const float4*)in)[i];
    ushort4 h, l;
    h.x = f2bf_rn(v.x); l.x = f2bf_rn(v.x - bf2f(h.x));
    h.y = f2bf_rn(v.y); l.y = f2bf_rn(v.y - bf2f(h.y));
    h.z = f2bf_rn(v.z); l.z = f2bf_rn(v.z - bf2f(h.z));
    h.w = f2bf_rn(v.w); l.w = f2bf_rn(v.w - bf2f(h.w));
    ((ushort4*)hi)[i] = h; ((ushort4*)lo)[i] = l;
}

// ---------------------------------------------------------------------------
// C[M,N] = A@W^T (+bias) via bf16x3: hi*hi + hi*lo + lo*hi, fp32 accum.
// Round 9: BK 32 -> 64 (half the vmcnt-drain barriers; 96 MFMA/wave/step).
// LDS 4 tiles x [128][64] ushort = 64 KB, 2 blocks/CU.
// Rule-21 both-sides XOR swizzle for the 128-B rows: stage source k-slot
// = s ^ (row&7) (gload_lds writes linearly); read slot = ks ^ (row&7).
// 8 consecutive rows hit 8 distinct banks -> 2 lanes/bank (free).
// gridDim.z = split-K; partial z writes C + z*MM*N.
// ---------------------------------------------------------------------------
__global__ __launch_bounds__(256, 2)
void gemm_bf16x3(const ushort* __restrict__ Ah, const ushort* __restrict__ Al,
                 const ushort* __restrict__ Bh, const ushort* __restrict__ Bl,
                 const float* __restrict__ bias, float* __restrict__ C,
                 int lda, int N, int kPerSplit)
{
    __shared__ ushort sAh[128*64], sAl[128*64], sBh[128*64], sBl[128*64];
    const int t    = threadIdx.x;
    const int bm   = blockIdx.y * 128, bn = blockIdx.x * 128;
    const int lane = t & 63, w = t >> 6;
    const int wr   = (w >> 1) * 64, wc = (w & 1) * 64;
    const int l16  = lane & 15;
    const int kbeg = blockIdx.z * kPerSplit;
    C += (size_t)blockIdx.z * MM * N;

    // --- staging: wave w covers rows [w*32, w*32+32) of each 128x64 tile ---
    // per call j (0..3): 64 lanes x 16B = 1 KB = rows w*32+j*8 .. +8
    const int srow    = w * 32 + (lane >> 3);            // + j*8
    const int srcslot = (lane & 7) ^ ((lane >> 3) & 7);  // inverse swizzle
    const ushort* gA = (size_t)(bm + srow) * lda + srcslot * 8 + kbeg + (const ushort*)0 + 0;
    const ushort* gAh = Ah + (size_t)(bm + srow) * lda + srcslot * 8 + kbeg;
    const ushort* gAl = Al + (size_t)(bm + srow) * lda + srcslot * 8 + kbeg;
    const ushort* gBh = Bh + (size_t)(bn + srow) * lda + srcslot * 8 + kbeg;
    const ushort* gBl = Bl + (size_t)(bn + srow) * lda + srcslot * 8 + kbeg;
    ushort* lAh = sAh + 2048 * w;   // wave-uniform LDS bases (+ j*512)
    ushort* lAl = sAl + 2048 * w;
    ushort* lBh = sBh + 2048 * w;
    ushort* lBl = sBl + 2048 * w;

    f32x4 acc[4][4];
    #pragma unroll
    for (int i = 0; i < 4; ++i)
        #pragma unroll
        for (int j = 0; j < 4; ++j)
            acc[i][j] = (f32x4){0.f, 0.f, 0.f, 0.f};

    for (int k0 = 0; k0 < kPerSplit; k0 += 64) {
        #pragma unroll
        for (int j = 0; j < 4; ++j) {
            const size_t go = (size_t)j * 8 * lda + k0;
            gload_lds16(gAh + go, lAh + j * 512);
            gload_lds16(gAl + go, lAl + j * 512);
            gload_lds16(gBh + go, lBh + j * 512);
            gload_lds16(gBl + go, lBl + j * 512);
        }
        __syncthreads();
        #pragma unroll
        for (int sub = 0; sub < 2; ++sub) {
            const int ks  = (sub << 2) | (lane >> 4);        // k-slot 0..7
            const int ssw = ks ^ (l16 & 7);                  // swizzled slot
            bf16x8 fbh[4], fbl[4];
            #pragma unroll
            for (int nj = 0; nj < 4; ++nj) {
                int off = (wc + nj * 16 + l16) * 64 + ssw * 8;
                fbh[nj] = *(const bf16x8*)(sBh + off);
                fbl[nj] = *(const bf16x8*)(sBl + off);
            }
            #pragma unroll
            for (int mi = 0; mi < 4; ++mi) {
                int off = (wr + mi * 16 + l16) * 64 + ssw * 8;
                bf16x8 fah = *(const bf16x8*)(sAh + off);
                bf16x8 fal = *(const bf16x8*)(sAl + off);
                #pragma unroll
                for (int nj = 0; nj < 4; ++nj) {
                    acc[mi][nj] = __builtin_amdgcn_mfma_f32_16x16x32_bf16(fah, fbh[nj], acc[mi][nj], 0, 0, 0);
                    acc[mi][nj] = __builtin_amdgcn_mfma_f32_16x16x32_bf16(fah, fbl[nj], acc[mi][nj], 0, 0, 0);
                    acc[mi][nj] = __builtin_amdgcn_mfma_f32_16x16x32_bf16(fal, fbh[nj], acc[mi][nj], 0, 0, 0);
                }
            }
        }
        __syncthreads();
    }
    // C/D layout: col = lane&15, row = (lane>>4)*4 + reg  [m89-verified]
    #pragma unroll
    for (int nj = 0; nj < 4; ++nj) {
        int col = bn + wc + nj * 16 + l16;
        float bb = bias ? bias[col] : 0.f;
        #pragma unroll
        for (int mi = 0; mi < 4; ++mi) {
            int row0 = bm + wr + mi * 16 + (lane >> 4) * 4;
            #pragma unroll
            for (int r = 0; r < 4; ++r)
                C[(size_t)(row0 + r) * N + col] = acc[mi][nj][r] + bb;
        }
    }
}

// ---------------------------------------------------------------------------
// out[M,D] = part0 + part1 + bias   (split-K combine for gemm2)
// ---------------------------------------------------------------------------
__global__ __launch_bounds__(256)
void combine2(const float* __restrict__ part, const float* __restrict__ ob,
              float* __restrict__ out)
{
    int i = blockIdx.x * 256 + threadIdx.x;        // MM*D_/4
    float4 a = ((const float4*)part)[i];
    float4 b = ((const float4*)(part + (size_t)MM * D_))[i];
    float4 bb = *(const float4*)(ob + ((i & (D_/4 - 1)) << 2));
    float4 o;
    o.x = a.x + b.x + bb.x; o.y = a.y + b.y + bb.y;
    o.z = a.z + b.z + bb.z; o.w = a.w + b.w + bb.w;
    ((float4*)out)[i] = o;
}

// ---------------------------------------------------------------------------
// u = silu(depthwise_conv3(h) + conv_b)  — float4-vectorized along di
// ---------------------------------------------------------------------------
__global__ __launch_bounds__(256)
void conv_silu(const float* __restrict__ h, const float* __restrict__ cw,
               const float* __restrict__ cb, float* __restrict__ u)
{
    size_t i4 = ((size_t)blockIdx.x * 256 + threadIdx.x) << 2;   // elem index
    int    di = (int)(i4 & (DI_ - 1));
    int    l  = (int)((i4 >> 11) & (L_ - 1));
    float4 cc = *(const float4*)(h + i4);
    float4 lf = make_float4(0.f, 0.f, 0.f, 0.f);
    float4 rt = make_float4(0.f, 0.f, 0.f, 0.f);
    if (l > 0)      lf = *(const float4*)(h + i4 - DI_);
    if (l < L_ - 1) rt = *(const float4*)(h + i4 + DI_);
    float4 bb = *(const float4*)(cb + di);
    float cin[4]  = {cc.x, cc.y, cc.z, cc.w};
    float lin[4]  = {lf.x, lf.y, lf.z, lf.w};
    float rin[4]  = {rt.x, rt.y, rt.z, rt.w};
    float bin[4]  = {bb.x, bb.y, bb.z, bb.w};
    float res[4];
    #pragma unroll
    for (int j = 0; j < 4; ++j) {
        const float* w = cw + (size_t)(di + j) * 3;
        float s = bin[j] + lin[j] * w[0] + cin[j] * w[1] + rin[j] * w[2];
        res[j] = s / (1.f + __expf(-s));
    }
    *(float4*)(u + i4) = make_float4(res[0], res[1], res[2], res[3]);
}

// ---------------------------------------------------------------------------
// xproj stage A: partial[s][m][c] = sum_{k in slice s} u[m][k]*xw[c][k]
// ---------------------------------------------------------------------------
__global__ __launch_bounds__(256)
void xprojA(const float* __restrict__ u, const float* __restrict__ xw,
            float* __restrict__ part)
{
    __shared__ float ut[32][132];
    __shared__ float wt[80][132];
    const int t  = threadIdx.x;
    const int bm = blockIdx.x * 32;
    const int ks = blockIdx.y;
    const int r2 = t & 15, cg = t >> 4;
    float acc[2][5] = {};
    for (int ch = 0; ch < 2; ++ch) {
        const int kb = ks * 256 + ch * 128;
        {
            int sr = t >> 3, k4 = (t & 7) * 4;
            #pragma unroll
            for (int i = 0; i < 4; ++i) {
                float4 v = *(const float4*)(u + (size_t)(bm + sr) * DI_ + kb + k4 + 32 * i);
                ut[sr][k4 + 32*i + 0] = v.x; ut[sr][k4 + 32*i + 1] = v.y;
                ut[sr][k4 + 32*i + 2] = v.z; ut[sr][k4 + 32*i + 3] = v.w;
            }
        }
        #pragma unroll
        for (int i = 0; i < 10; ++i) {
            int idx = t + 256 * i;
            int wrow = idx >> 5, k4 = (idx & 31) * 4;
            float4 v = *(const float4*)(xw + (size_t)wrow * DI_ + kb + k4);
            wt[wrow][k4 + 0] = v.x; wt[wrow][k4 + 1] = v.y;
            wt[wrow][k4 + 2] = v.z; wt[wrow][k4 + 3] = v.w;
        }
        __syncthreads();
        for (int k = 0; k < 128; k += 4) {
            float4 u0 = *(const float4*)&ut[r2][k];
            float4 u1 = *(const float4*)&ut[r2 + 16][k];
            #pragma unroll
            for (int c = 0; c < 5; ++c) {
                float4 wv = *(const float4*)&wt[cg * 5 + c][k];
                acc[0][c] = fmaf(u0.x, wv.x, fmaf(u0.y, wv.y, fmaf(u0.z, wv.z, fmaf(u0.w, wv.w, acc[0][c]))));
                acc[1][c] = fmaf(u1.x, wv.x, fmaf(u1.y, wv.y, fmaf(u1.z, wv.z, fmaf(u1.w, wv.w, acc[1][c]))));
            }
        }
        __syncthreads();
    }
    size_t b0 = ((size_t)ks * MM + bm + r2) * 80 + cg * 5;
    size_t b1 = ((size_t)ks * MM + bm + r2 + 16) * 80 + cg * 5;
    #pragma unroll
    for (int c = 0; c < 5; ++c) { part[b0 + c] = acc[0][c]; part[b1 + c] = acc[1][c]; }
}

__global__ __launch_bounds__(256)
void xprojB(const float* __restrict__ part, const float* __restrict__ xpb,
            float* __restrict__ xdbl)
{
    int idx = blockIdx.x * 256 + threadIdx.x;   // MM*80
    int c = idx % 80;
    float s = xpb[c];
    #pragma unroll
    for (int sl = 0; sl < XKS; ++sl)
        s += part[(size_t)sl * (MM * 80) + idx];
    xdbl[idx] = s;
}

__global__ __launch_bounds__(256)
void transpose_dtw(const float* __restrict__ dtw, float* __restrict__ dtwT)
{
    int idx = blockIdx.x * 256 + threadIdx.x;   // RR*DI
    int di  = idx & (DI_ - 1);
    int r   = idx >> 11;
    dtwT[(size_t)r * DI_ + di] = dtw[(size_t)di * RR + r];
}

// ---------------------------------------------------------------------------
// delta[M,DI] = softplus(xdbl[:, :64] @ dtwT + dt_b)
// ---------------------------------------------------------------------------
__global__ __launch_bounds__(256)
void delta_gemm(const float* __restrict__ xdbl, const float* __restrict__ dtwT,
                const float* __restrict__ dtb, float* __restrict__ delta)
{
    __shared__ float dl[16][64];
    const int t    = threadIdx.x;
    const int row0 = blockIdx.y * 16;
    const int col  = blockIdx.x * 256 + t;
    {
        int sr = t >> 4, sk = (t & 15) << 2;
        float4 v = *(const float4*)(xdbl + (size_t)(row0 + sr) * 80 + sk);
        dl[sr][sk] = v.x; dl[sr][sk+1] = v.y; dl[sr][sk+2] = v.z; dl[sr][sk+3] = v.w;
    }
    __syncthreads();
    float acc[16] = {};
    for (int k = 0; k < 64; ++k) {
        float w = dtwT[(size_t)k * DI_ + col];
        #pragma unroll
        for (int rr = 0; rr < 16; ++rr)
            acc[rr] = fmaf(dl[rr][k], w, acc[rr]);
    }
    float bias = dtb[col];
    #pragma unroll
    for (int rr = 0; rr < 16; ++rr) {
        float x  = acc[rr] + bias;
        float sp = fmaxf(x, 0.f) + log1pf(__expf(-fabsf(x)));
        delta[(size_t)(row0 + rr) * DI_ + col] = sp;
    }
}

// ---------------------------------------------------------------------------
// Scan pass A: per (b, chunk, di) compute P[n]=prod(dA), S[n]=scan-from-zero
// ---------------------------------------------------------------------------
__global__ __launch_bounds__(256)
void scanA(const float* __restrict__ delta, const float* __restrict__ u,
           const float* __restrict__ xdbl, const float* __restrict__ A_log,
           float* __restrict__ Pbuf, float* __restrict__ Sbuf)
{
    const int tid  = blockIdx.x * 256 + threadIdx.x;   // B*NC*DI
    const int di   = tid & (DI_ - 1);
    const int rest = tid >> 11;
    const int ch   = rest & (NC - 1);
    const int b    = rest >> 6;
    float A2[NS];
    {
        const float4* ap = (const float4*)(A_log + (size_t)di * NS);
        #pragma unroll
        for (int q = 0; q < 4; ++q) {
            float4 v = ap[q];
            A2[q*4+0] = -__expf(v.x) * 1.44269504f;
            A2[q*4+1] = -__expf(v.y) * 1.44269504f;
            A2[q*4+2] = -__expf(v.z) * 1.44269504f;
            A2[q*4+3] = -__expf(v.w) * 1.44269504f;
        }
    }
    float c[NS], P[NS];
    #pragma unroll
    for (int n = 0; n < NS; ++n) { c[n] = 0.f; P[n] = 1.f; }
    const size_t l0 = (size_t)b * L_ + (size_t)ch * CL;
    const float* dp = delta + l0 * DI_ + di;
    const float* up = u     + l0 * DI_ + di;
    const float* xp = xdbl  + l0 * 80 + RR;
    for (int l = 0; l < CL; ++l) {
        float dlt = dp[(size_t)l * DI_];
        float du  = dlt * up[(size_t)l * DI_];
        const float4* bp = (const float4*)(xp + (size_t)l * 80);
        #pragma unroll
        for (int q = 0; q < 4; ++q) {
            float4 bv = bp[q];
            float bn_[4] = {bv.x, bv.y, bv.z, bv.w};
            #pragma unroll
            for (int j = 0; j < 4; ++j) {
                int   n = q * 4 + j;
                float a = exp2f(dlt * A2[n]);
                c[n] = fmaf(a, c[n], du * bn_[j]);
                P[n] *= a;
            }
        }
    }
    float4* Pp = (float4*)(Pbuf + (size_t)tid * NS);
    float4* Sp = (float4*)(Sbuf + (size_t)tid * NS);
    #pragma unroll
    for (int q = 0; q < 4; ++q) {
        Pp[q] = make_float4(P[q*4], P[q*4+1], P[q*4+2], P[q*4+3]);
        Sp[q] = make_float4(c[q*4], c[q*4+1], c[q*4+2], c[q*4+3]);
    }
}

__global__ __launch_bounds__(256)
void scanB(const float* __restrict__ Pbuf, const float* __restrict__ Sbuf,
           float* __restrict__ start)
{
    const int tid = blockIdx.x * 256 + threadIdx.x;   // B*DI*NS
    const int n   = tid & (NS - 1);
    const int di  = (tid >> 4) & (DI_ - 1);
    const int b   = tid >> 15;
    float c = 0.f;
    for (int ch = 0; ch < NC; ++ch) {
        size_t idx = ((size_t)(b * NC + ch) * DI_ + di) * NS + n;
        start[idx] = c;
        c = fmaf(Pbuf[idx], c, Sbuf[idx]);
    }
}

// ---------------------------------------------------------------------------
// Scan pass C: replay from start state; y emitted directly as bf16 hi/lo
// ---------------------------------------------------------------------------
__global__ __launch_bounds__(256)
void scanC(const float* __restrict__ delta, const float* __restrict__ u,
           const float* __restrict__ xdbl, const float* __restrict__ A_log,
           const float* __restrict__ Dp, const float* __restrict__ start,
           ushort* __restrict__ yh, ushort* __restrict__ yl)
{
    const int tid  = blockIdx.x * 256 + threadIdx.x;
    const int di   = tid & (DI_ - 1);
    const int rest = tid >> 11;
    const int ch   = rest & (NC - 1);
    const int b    = rest >> 6;
    float A2[NS];
    {
        const float4* ap = (const float4*)(A_log + (size_t)di * NS);
        #pragma unroll
        for (int q = 0; q < 4; ++q) {
            float4 v = ap[q];
            A2[q*4+0] = -__expf(v.x) * 1.44269504f;
            A2[q*4+1] = -__expf(v.y) * 1.44269504f;
            A2[q*4+2] = -__expf(v.z) * 1.44269504f;
            A2[q*4+3] = -__expf(v.w) * 1.44269504f;
        }
    }
    float c[NS];
    {
        const float4* sp = (const float4*)(start + (size_t)tid * NS);
        #pragma unroll
        for (int q = 0; q < 4; ++q) {
            float4 v = sp[q];
            c[q*4+0] = v.x; c[q*4+1] = v.y; c[q*4+2] = v.z; c[q*4+3] = v.w;
        }
    }
    const float Dpar = Dp[di];
    const size_t l0 = (size_t)b * L_ + (size_t)ch * CL;
    const float* dp = delta + l0 * DI_ + di;
    const float* up = u     + l0 * DI_ + di;
    const float* xp = xdbl  + l0 * 80 + RR;
    for (int l = 0; l < CL; ++l) {
        float dlt = dp[(size_t)l * DI_];
        float uu  = up[(size_t)l * DI_];
        float du  = dlt * uu;
        const float4* bp = (const float4*)(xp + (size_t)l * 80);
        float sum = 0.f;
        #pragma unroll
        for (int q = 0; q < 4; ++q) {
            float4 bv = bp[q];
            float bn_[4] = {bv.x, bv.y, bv.z, bv.w};
            #pragma unroll
            for (int j = 0; j < 4; ++j) {
                int   n = q * 4 + j;
                float a = exp2f(dlt * A2[n]);
                c[n] = fmaf(a, c[n], du * bn_[j]);
                sum += c[n];
            }
        }
        float y = sum + uu * Dpar;
        ushort hb = f2bf_rn(y);
        size_t oi = (l0 + l) * DI_ + di;
        yh[oi] = hb;
        yl[oi] = f2bf_rn(y - bf2f(hb));
    }
}

// ---------------------------------------------------------------------------
extern "C" void kernel_launch(void* const* d_in, const int* in_sizes, int n_in,
                              void* d_out, int out_size, void* d_ws, size_t ws_size,
                              hipStream_t stream)
{
    const float* x      = (const float*)d_in[0];
    const float* in_w   = (const float*)d_in[1];
    const float* in_b   = (const float*)d_in[2];
    const float* conv_w = (const float*)d_in[3];
    const float* conv_b = (const float*)d_in[4];
    const float* xpw    = (const float*)d_in[5];
    const float* xpb    = (const float*)d_in[6];
    const float* dt_w   = (const float*)d_in[7];
    const float* dt_b   = (const float*)d_in[8];
    const float* A_log  = (const float*)d_in[9];
    const float* Dpar   = (const float*)d_in[10];
    const float* out_w  = (const float*)d_in[11];
    const float* out_b  = (const float*)d_in[12];
    float*       out    = (float*)d_out;

    char* ws  = (char*)d_ws;
    size_t off = 0;
    auto alloc = [&](size_t bytes) {
        void* p = ws + off; off = (off + bytes + 255) & ~(size_t)255; return p;
    };
    float*  u_    = (float*)alloc((size_t)MM * DI_ * 4);   // u; later gemm2 partials
    float*  h_    = (float*)alloc((size_t)MM * DI_ * 4);   // h -> delta
    float*  xdbl  = (float*)alloc((size_t)MM * 80 * 4);
    float*  dtwT  = (float*)alloc((size_t)RR * DI_ * 4);
    ushort* yh    = (ushort*)alloc((size_t)MM * DI_ * 2);  // aliases: xpart, Pbuf (16.8MB)
    ushort* yl    = (ushort*)alloc((size_t)MM * DI_ * 2);  // aliases: Sbuf (16.8MB)
    ushort* xh    = (ushort*)alloc((size_t)MM * D_ * 2);   // dead after gemm1
    ushort* xl    = (ushort*)alloc((size_t)MM * D_ * 2);   //   -> stbuf aliases xh+xl
    ushort* wih   = (ushort*)alloc((size_t)DI_ * D_ * 2);
    ushort* wil   = (ushort*)alloc((size_t)DI_ * D_ * 2);
    ushort* woh   = (ushort*)alloc((size_t)D_ * DI_ * 2);
    ushort* wol   = (ushort*)alloc((size_t)D_ * DI_ * 2);
    float*  xpart = (float*)yh;     // 10.5 MB <= 16.8 MB
    float*  Pbuf  = (float*)yh;     // NC=64: B*NC*DI*NS*4 = 16.8 MB (exact fit)
    float*  Sbuf  = (float*)yl;
    float*  stbuf = (float*)xh;     // 16.8 MB spans xh+xl (both dead after gemm1)
    float*  part2 = u_;             // gemm2 split-K partials (2x16.8 = 33.6 MB)

    // 0. bf16 hi/lo conversions
    cvt_hilo<<<(MM * D_ / 4 + 255) / 256, 256, 0, stream>>>(x, xh, xl, MM * D_ / 4);
    cvt_hilo<<<(DI_ * D_ / 4 + 255) / 256, 256, 0, stream>>>(in_w, wih, wil, DI_ * D_ / 4);
    cvt_hilo<<<(D_ * DI_ / 4 + 255) / 256, 256, 0, stream>>>(out_w, woh, wol, D_ * DI_ / 4);
    // 1. h = x @ in_w^T + in_b   [4096 x 2048], K=1024 (16 K-steps of 64)
    gemm_bf16x3<<<dim3(DI_ / 128, MM / 128, 1), 256, 0, stream>>>(
        xh, xl, wih, wil, in_b, h_, D_, DI_, D_);
    // 2. u = silu(conv3(h) + conv_b)
    conv_silu<<<(MM * DI_ / 4) / 256, 256, 0, stream>>>(h_, conv_w, conv_b, u_);
    // 3. x_dbl = u @ x_proj_w^T + x_proj_b  (split-K two-stage)
    xprojA<<<dim3(MM / 32, XKS), 256, 0, stream>>>(u_, xpw, xpart);
    xprojB<<<(MM * 80) / 256, 256, 0, stream>>>(xpart, xpb, xdbl);
    // 4. dt_w transpose
    transpose_dtw<<<(RR * DI_) / 256, 256, 0, stream>>>(dt_w, dtwT);
    // 5. delta = softplus(delta_lr @ dt_w^T + dt_b)  -> h_
    delta_gemm<<<dim3(DI_ / 256, MM / 16), 256, 0, stream>>>(xdbl, dtwT, dt_b, h_);
    // 6-8. chunked selective scan (NC=64); y emitted as bf16 hi/lo
    scanA<<<(B_ * NC * DI_) / 256, 256, 0, stream>>>(h_, u_, xdbl, A_log, Pbuf, Sbuf);
    scanB<<<(B_ * DI_ * NS) / 256, 256, 0, stream>>>(Pbuf, Sbuf, stbuf);
    scanC<<<(B_ * NC * DI_) / 256, 256, 0, stream>>>(h_, u_, xdbl, A_log, Dpar, stbuf, yh, yl);
    // 9. out = y @ out_w^T + out_b  [4096 x 1024], K=2048, split-K=2 (16 K-steps)
    gemm_bf16x3<<<dim3(D_ / 128, MM / 128, 2), 256, 0, stream>>>(
        yh, yl, woh, wol, nullptr, part2, DI_, D_, DI_ / 2);
    combine2<<<(MM * D_ / 4) / 256, 256, 0, stream>>>(part2, out_b, out);
}